// Round 1
// baseline (321.988 us; speedup 1.0000x reference)
//
#include <hip/hip_runtime.h>
#include <math.h>

#define FEATD 128
#define NNODES 10000
#define NBATCH 4

// ws layout (floats)
#define OFF_WT 0                    // Wt[128][64]: Wt[k][j] = W1n[j][k] (j<32), W1n[j-32][128+k] (j>=32)
#define SZ_WT (128*64)
#define OFF_W1L (OFF_WT + SZ_WT)    // 8192: w1last_n[32] = W1n[:,256]
#define OFF_W2  (OFF_W1L + 32)      // 8224: W2n[32][32] row-major
#define OFF_W3  (OFF_W2 + 1024)     // 9248: W3n[32]
#define OFF_P   (OFF_W3 + 32)       // 9280: P[40000][64] (src-proj 0:32, tgt-proj 32:64)
#define P_FLOATS (NBATCH*NNODES*64) // 2,560,000

// ---------------- block-wide sum (256 threads, wave=64) ----------------
__device__ __forceinline__ float block_sum(float val, volatile float* red) {
  #pragma unroll
  for (int off = 1; off < 64; off <<= 1) val += __shfl_xor(val, off, 64);
  int tid = threadIdx.x;
  if ((tid & 63) == 0) red[tid >> 6] = val;
  __syncthreads();
  if (tid == 0) {
    float t = red[0];
    int nw = (blockDim.x + 63) >> 6;
    for (int i = 1; i < nw; ++i) t += red[i];
    red[0] = t;
  }
  __syncthreads();
  float t = red[0];
  __syncthreads();
  return t;
}

// ---------------- spectral norm sigma (exact reference algorithm, fp32) ----------------
__device__ float spectral_sigma(const float* Wg, int M, int K,
                                float* sW, float* u, float* v, volatile float* red) {
  int tid = threadIdx.x, nt = blockDim.x;
  for (int i = tid; i < M * K; i += nt) sW[i] = Wg[i];
  float u0 = 1.0f / sqrtf((float)M);
  for (int j = tid; j < M; j += nt) u[j] = u0;
  __syncthreads();
  for (int it = 0; it < 5; ++it) {
    // v = W^T u
    for (int k = tid; k < K; k += nt) {
      float a = 0.f;
      for (int j = 0; j < M; ++j) a += sW[j * K + k] * u[j];
      v[k] = a;
    }
    __syncthreads();
    float p = 0.f;
    for (int k = tid; k < K; k += nt) p += v[k] * v[k];
    p = block_sum(p, red);
    float invv = 1.0f / (sqrtf(p) + 1e-12f);
    for (int k = tid; k < K; k += nt) v[k] *= invv;
    __syncthreads();
    // u = W v
    for (int j = tid; j < M; j += nt) {
      float a = 0.f;
      for (int k = 0; k < K; ++k) a += sW[j * K + k] * v[k];
      u[j] = a;
    }
    __syncthreads();
    float q = 0.f;
    for (int j = tid; j < M; j += nt) q += u[j] * u[j];
    q = block_sum(q, red);
    float invu = 1.0f / (sqrtf(q) + 1e-12f);
    for (int j = tid; j < M; j += nt) u[j] *= invu;
    __syncthreads();
  }
  // sigma = u . (W v)
  float s = 0.f;
  for (int j = tid; j < M; j += nt) {
    float a = 0.f;
    for (int k = 0; k < K; ++k) a += sW[j * K + k] * v[k];
    s += u[j] * a;
  }
  s = block_sum(s, red);
  return s;
}

__global__ __launch_bounds__(256) void spectral_kernel(const float* __restrict__ W1,
                                                       const float* __restrict__ W2,
                                                       const float* __restrict__ W3,
                                                       float* __restrict__ ws) {
  __shared__ float sW[32 * 257];
  __shared__ float u[32], v[257];
  __shared__ float red[8];
  int tid = threadIdx.x, nt = blockDim.x;

  float sig1 = spectral_sigma(W1, 32, 257, sW, u, v, red);
  float i1 = 1.0f / sig1;
  // Wt[k][j]
  for (int idx = tid; idx < 128 * 64; idx += nt) {
    int k = idx >> 6, jj = idx & 63;
    float w = (jj < 32) ? sW[jj * 257 + k] : sW[(jj - 32) * 257 + 128 + k];
    ws[OFF_WT + idx] = w * i1;
  }
  for (int j = tid; j < 32; j += nt) ws[OFF_W1L + j] = sW[j * 257 + 256] * i1;
  __syncthreads();

  float sig2 = spectral_sigma(W2, 32, 32, sW, u, v, red);
  float i2 = 1.0f / sig2;
  for (int idx = tid; idx < 1024; idx += nt) ws[OFF_W2 + idx] = sW[idx] * i2;
  __syncthreads();

  float sig3 = spectral_sigma(W3, 1, 32, sW, u, v, red);
  float i3 = 1.0f / sig3;
  for (int k = tid; k < 32; k += nt) ws[OFF_W3 + k] = sW[k] * i3;
}

// ---------------- per-node projection precompute ----------------
// P[row][j]   (j<32)  = sum_k feat[row][k] * W1n[j][k]
// P[row][32+j]        = sum_k feat[row][k] * W1n[j][128+k]
__global__ __launch_bounds__(256) void project_kernel(const float* __restrict__ feat,
                                                      float* __restrict__ ws) {
  __shared__ float sW[128 * 64];  // 32 KB
  float* P = ws + OFF_P;
  int tid = threadIdx.x;
  for (int i = tid * 4; i < 128 * 64; i += 256 * 4)
    *(float4*)&sW[i] = *(const float4*)&ws[OFF_WT + i];
  __syncthreads();

  int nl = tid >> 3;            // 0..31 node within chunk
  int jg = (tid & 7) << 3;      // 0,8,...,56 output group
  for (int c = blockIdx.x; c < (NBATCH * NNODES) / 32; c += gridDim.x) {
    int row = c * 32 + nl;
    const float4* F = (const float4*)&feat[(size_t)row * FEATD];
    float acc[8] = {0, 0, 0, 0, 0, 0, 0, 0};
    #pragma unroll 4
    for (int k4 = 0; k4 < 32; ++k4) {
      float4 f = F[k4];
      #pragma unroll
      for (int kk = 0; kk < 4; ++kk) {
        int k = 4 * k4 + kk;
        float fv = (kk == 0) ? f.x : (kk == 1) ? f.y : (kk == 2) ? f.z : f.w;
        float4 w0 = *(const float4*)&sW[k * 64 + jg];
        float4 w1 = *(const float4*)&sW[k * 64 + jg + 4];
        acc[0] += fv * w0.x; acc[1] += fv * w0.y; acc[2] += fv * w0.z; acc[3] += fv * w0.w;
        acc[4] += fv * w1.x; acc[5] += fv * w1.y; acc[6] += fv * w1.z; acc[7] += fv * w1.w;
      }
    }
    float4 o0 = make_float4(acc[0], acc[1], acc[2], acc[3]);
    float4 o1 = make_float4(acc[4], acc[5], acc[6], acc[7]);
    *(float4*)&P[(size_t)row * 64 + jg] = o0;
    *(float4*)&P[(size_t)row * 64 + jg + 4] = o1;
  }
}

// ---------------- shared MLP tail: h1[32] -> (edge_weight, logAlpha) ----------------
__device__ __forceinline__ void mlp_tail(const float* h1, const float* sW2, const float* sW3,
                                         const float* sB2, float bias3,
                                         float* out, int e, int E) {
  float la = bias3;
  #pragma unroll
  for (int j = 0; j < 32; ++j) {
    float acc = sB2[j];
    #pragma unroll
    for (int q = 0; q < 8; ++q) {
      float4 w = *(const float4*)&sW2[j * 32 + 4 * q];
      acc += w.x * h1[4 * q] + w.y * h1[4 * q + 1] + w.z * h1[4 * q + 2] + w.w * h1[4 * q + 3];
    }
    la += sW3[j] * fmaxf(acc, 0.f);
  }
  la = fminf(fmaxf(la, -5.f), 5.f);
  out[e] = 1.0f / (1.0f + __expf(-la / 0.66f));
  out[E + e] = la;
}

// ---------------- main per-edge kernel (uses precomputed P) ----------------
__global__ __launch_bounds__(256) void edge_kernel(const float* __restrict__ feat,
                                                   const float* __restrict__ ws,
                                                   const float* __restrict__ b1,
                                                   const float* __restrict__ b2,
                                                   const float* __restrict__ b3,
                                                   const int* __restrict__ bids,
                                                   const int* __restrict__ srcs,
                                                   const int* __restrict__ tgts,
                                                   float* __restrict__ out, int E) {
  __shared__ float sW2[1024];
  __shared__ float sW3[32], sW1l[32], sB1[32], sB2[32];
  int tid = threadIdx.x;
  for (int i = tid; i < 1024; i += 256) sW2[i] = ws[OFF_W2 + i];
  if (tid < 32) {
    sW3[tid]  = ws[OFF_W3 + tid];
    sW1l[tid] = ws[OFF_W1L + tid];
    sB1[tid]  = b1[tid];
    sB2[tid]  = b2[tid];
  }
  __syncthreads();
  float bias3 = b3[0];
  const float* P = ws + OFF_P;

  for (int e = blockIdx.x * 256 + tid; e < E; e += gridDim.x * 256) {
    int b = bids[e], s = srcs[e], t = tgts[e];
    int rs = b * NNODES + s;
    int rt = b * NNODES + t;
    const float4* A  = (const float4*)&feat[(size_t)rs * FEATD];
    const float4* Bp = (const float4*)&feat[(size_t)rt * FEATD];
    float ssd = 0.f;
    #pragma unroll
    for (int k = 0; k < 32; ++k) {
      float4 a = A[k], c = Bp[k];
      float dx = a.x - c.x, dy = a.y - c.y, dz = a.z - c.z, dw = a.w - c.w;
      ssd += dx * dx + dy * dy + dz * dz + dw * dw;
    }
    float dist = sqrtf(ssd);

    const float4* Ps = (const float4*)&P[(size_t)rs * 64];
    const float4* Pt = (const float4*)&P[(size_t)rt * 64 + 32];
    float h1[32];
    #pragma unroll
    for (int q = 0; q < 8; ++q) {
      float4 ps = Ps[q], pt = Pt[q];
      h1[4*q+0] = fmaxf(ps.x + pt.x + dist * sW1l[4*q+0] + sB1[4*q+0], 0.f);
      h1[4*q+1] = fmaxf(ps.y + pt.y + dist * sW1l[4*q+1] + sB1[4*q+1], 0.f);
      h1[4*q+2] = fmaxf(ps.z + pt.z + dist * sW1l[4*q+2] + sB1[4*q+2], 0.f);
      h1[4*q+3] = fmaxf(ps.w + pt.w + dist * sW1l[4*q+3] + sB1[4*q+3], 0.f);
    }
    mlp_tail(h1, sW2, sW3, sB2, bias3, out, e, E);
  }
}

// ---------------- fallback: no P array (small ws) — W1 applied in-loop ----------------
__global__ __launch_bounds__(256) void edge_kernel_nop(const float* __restrict__ feat,
                                                       const float* __restrict__ ws,
                                                       const float* __restrict__ b1,
                                                       const float* __restrict__ b2,
                                                       const float* __restrict__ b3,
                                                       const int* __restrict__ bids,
                                                       const int* __restrict__ srcs,
                                                       const int* __restrict__ tgts,
                                                       float* __restrict__ out, int E) {
  __shared__ float sWt[128 * 64];  // 32 KB
  __shared__ float sW2[1024];
  __shared__ float sW3[32], sW1l[32], sB1[32], sB2[32];
  int tid = threadIdx.x;
  for (int i = tid * 4; i < 128 * 64; i += 256 * 4)
    *(float4*)&sWt[i] = *(const float4*)&ws[OFF_WT + i];
  for (int i = tid; i < 1024; i += 256) sW2[i] = ws[OFF_W2 + i];
  if (tid < 32) {
    sW3[tid]  = ws[OFF_W3 + tid];
    sW1l[tid] = ws[OFF_W1L + tid];
    sB1[tid]  = b1[tid];
    sB2[tid]  = b2[tid];
  }
  __syncthreads();
  float bias3 = b3[0];

  for (int e = blockIdx.x * 256 + tid; e < E; e += gridDim.x * 256) {
    int b = bids[e], s = srcs[e], t = tgts[e];
    const float4* A  = (const float4*)&feat[(size_t)(b * NNODES + s) * FEATD];
    const float4* Bp = (const float4*)&feat[(size_t)(b * NNODES + t) * FEATD];
    float ssd = 0.f;
    float h1p[32];
    #pragma unroll
    for (int j = 0; j < 32; ++j) h1p[j] = 0.f;
    #pragma unroll 1
    for (int k4 = 0; k4 < 32; ++k4) {
      float4 a = A[k4], c = Bp[k4];
      float dx = a.x - c.x, dy = a.y - c.y, dz = a.z - c.z, dw = a.w - c.w;
      ssd += dx * dx + dy * dy + dz * dz + dw * dw;
      #pragma unroll
      for (int kk = 0; kk < 4; ++kk) {
        int k = 4 * k4 + kk;
        float fa = (kk == 0) ? a.x : (kk == 1) ? a.y : (kk == 2) ? a.z : a.w;
        float fc = (kk == 0) ? c.x : (kk == 1) ? c.y : (kk == 2) ? c.z : c.w;
        #pragma unroll
        for (int q = 0; q < 8; ++q) {
          float4 w0 = *(const float4*)&sWt[k * 64 + 4 * q];
          float4 w1 = *(const float4*)&sWt[k * 64 + 32 + 4 * q];
          h1p[4*q+0] += fa * w0.x + fc * w1.x;
          h1p[4*q+1] += fa * w0.y + fc * w1.y;
          h1p[4*q+2] += fa * w0.z + fc * w1.z;
          h1p[4*q+3] += fa * w0.w + fc * w1.w;
        }
      }
    }
    float dist = sqrtf(ssd);
    float h1[32];
    #pragma unroll
    for (int j = 0; j < 32; ++j)
      h1[j] = fmaxf(h1p[j] + dist * sW1l[j] + sB1[j], 0.f);
    mlp_tail(h1, sW2, sW3, sB2, bias3, out, e, E);
  }
}

extern "C" void kernel_launch(void* const* d_in, const int* in_sizes, int n_in,
                              void* d_out, int out_size, void* d_ws, size_t ws_size,
                              hipStream_t stream) {
  const float* feat = (const float*)d_in[0];
  const float* W1   = (const float*)d_in[1];
  const float* b1   = (const float*)d_in[2];
  const float* W2   = (const float*)d_in[3];
  const float* b2   = (const float*)d_in[4];
  const float* W3   = (const float*)d_in[5];
  const float* b3   = (const float*)d_in[6];
  const int* bids   = (const int*)d_in[7];
  const int* srcs   = (const int*)d_in[8];
  const int* tgts   = (const int*)d_in[9];
  float* out = (float*)d_out;
  float* ws  = (float*)d_ws;
  int E = in_sizes[7];

  spectral_kernel<<<dim3(1), dim3(256), 0, stream>>>(W1, W2, W3, ws);

  size_t need_full = (size_t)(OFF_P + P_FLOATS) * sizeof(float);
  int egrid = (E + 255) / 256;
  if (ws_size >= need_full) {
    project_kernel<<<dim3(625), dim3(256), 0, stream>>>(feat, ws);
    edge_kernel<<<dim3(egrid), dim3(256), 0, stream>>>(feat, ws, b1, b2, b3,
                                                       bids, srcs, tgts, out, E);
  } else {
    edge_kernel_nop<<<dim3(egrid), dim3(256), 0, stream>>>(feat, ws, b1, b2, b3,
                                                           bids, srcs, tgts, out, E);
  }
}

// Round 2
// 182.361 us; speedup vs baseline: 1.7657x; 1.7657x over previous
//
#include <hip/hip_runtime.h>
#include <hip/hip_fp16.h>
#include <math.h>

#define FEATD 128
#define NNODES 10000
#define NBATCH 4

// ws layout (float units)
#define OFF_WT 0                    // Wt[128][64]: Wt[k][j] = W1n[j][k] (j<32), W1n[j-32][128+k] (j>=32)
#define SZ_WT (128*64)
#define OFF_W1L (OFF_WT + SZ_WT)    // 8192: w1last_n[32] = W1n[:,256]
#define OFF_W2  (OFF_W1L + 32)      // 8224: W2n[32][32] row-major
#define OFF_W3  (OFF_W2 + 1024)     // 9248: W3n[32]
#define OFF_P   (OFF_W3 + 32)       // 9280: P[40000][64] (src-proj 0:32, tgt-proj 32:64)
#define P_FLOATS (NBATCH*NNODES*64) // 2,560,000
#define OFF_F16 (OFF_P + P_FLOATS)  // feat16[40000][128] __half, 10.24 MB

// ---------------- block-wide sum (256 threads, wave=64) ----------------
__device__ __forceinline__ float block_sum(float val, volatile float* red) {
  #pragma unroll
  for (int off = 1; off < 64; off <<= 1) val += __shfl_xor(val, off, 64);
  int tid = threadIdx.x;
  if ((tid & 63) == 0) red[tid >> 6] = val;
  __syncthreads();
  if (tid == 0) {
    float t = red[0];
    int nw = (blockDim.x + 63) >> 6;
    for (int i = 1; i < nw; ++i) t += red[i];
    red[0] = t;
  }
  __syncthreads();
  float t = red[0];
  __syncthreads();
  return t;
}

// ---------------- spectral norm sigma (exact reference algorithm, fp32) ----------------
__device__ float spectral_sigma(const float* Wg, int M, int K,
                                float* sW, float* u, float* v, volatile float* red) {
  int tid = threadIdx.x, nt = blockDim.x;
  for (int i = tid; i < M * K; i += nt) sW[i] = Wg[i];
  float u0 = 1.0f / sqrtf((float)M);
  for (int j = tid; j < M; j += nt) u[j] = u0;
  __syncthreads();
  for (int it = 0; it < 5; ++it) {
    // v = W^T u
    for (int k = tid; k < K; k += nt) {
      float a = 0.f;
      for (int j = 0; j < M; ++j) a += sW[j * K + k] * u[j];
      v[k] = a;
    }
    __syncthreads();
    float p = 0.f;
    for (int k = tid; k < K; k += nt) p += v[k] * v[k];
    p = block_sum(p, red);
    float invv = 1.0f / (sqrtf(p) + 1e-12f);
    for (int k = tid; k < K; k += nt) v[k] *= invv;
    __syncthreads();
    // u = W v
    for (int j = tid; j < M; j += nt) {
      float a = 0.f;
      for (int k = 0; k < K; ++k) a += sW[j * K + k] * v[k];
      u[j] = a;
    }
    __syncthreads();
    float q = 0.f;
    for (int j = tid; j < M; j += nt) q += u[j] * u[j];
    q = block_sum(q, red);
    float invu = 1.0f / (sqrtf(q) + 1e-12f);
    for (int j = tid; j < M; j += nt) u[j] *= invu;
    __syncthreads();
  }
  // sigma = u . (W v)
  float s = 0.f;
  for (int j = tid; j < M; j += nt) {
    float a = 0.f;
    for (int k = 0; k < K; ++k) a += sW[j * K + k] * v[k];
    s += u[j] * a;
  }
  s = block_sum(s, red);
  return s;
}

__global__ __launch_bounds__(256) void spectral_kernel(const float* __restrict__ W1,
                                                       const float* __restrict__ W2,
                                                       const float* __restrict__ W3,
                                                       float* __restrict__ ws) {
  __shared__ float sW[32 * 257];
  __shared__ float u[32], v[257];
  __shared__ float red[8];
  int tid = threadIdx.x, nt = blockDim.x;

  float sig1 = spectral_sigma(W1, 32, 257, sW, u, v, red);
  float i1 = 1.0f / sig1;
  for (int idx = tid; idx < 128 * 64; idx += nt) {
    int k = idx >> 6, jj = idx & 63;
    float w = (jj < 32) ? sW[jj * 257 + k] : sW[(jj - 32) * 257 + 128 + k];
    ws[OFF_WT + idx] = w * i1;
  }
  for (int j = tid; j < 32; j += nt) ws[OFF_W1L + j] = sW[j * 257 + 256] * i1;
  __syncthreads();

  float sig2 = spectral_sigma(W2, 32, 32, sW, u, v, red);
  float i2 = 1.0f / sig2;
  for (int idx = tid; idx < 1024; idx += nt) ws[OFF_W2 + idx] = sW[idx] * i2;
  __syncthreads();

  float sig3 = spectral_sigma(W3, 1, 32, sW, u, v, red);
  float i3 = 1.0f / sig3;
  for (int k = tid; k < 32; k += nt) ws[OFF_W3 + k] = sW[k] * i3;
}

// ---------------- per-node projection precompute (+ optional fp16 feat copy) ----------------
// P[row][j]   (j<32)  = sum_k feat[row][k] * W1n[j][k]
// P[row][32+j]        = sum_k feat[row][k] * W1n[j][128+k]
__global__ __launch_bounds__(256) void project_kernel(const float* __restrict__ feat,
                                                      float* __restrict__ ws,
                                                      __half* __restrict__ f16,
                                                      int doF16) {
  __shared__ float sW[128 * 64];  // 32 KB
  float* P = ws + OFF_P;
  int tid = threadIdx.x;
  for (int i = tid * 4; i < 128 * 64; i += 256 * 4)
    *(float4*)&sW[i] = *(const float4*)&ws[OFF_WT + i];
  __syncthreads();

  int nl = tid >> 3;            // 0..31 node within chunk
  int jg = (tid & 7) << 3;      // 0,8,...,56 output group
  int slice = (tid & 7);        // k4 slice owner for f16 write
  for (int c = blockIdx.x; c < (NBATCH * NNODES) / 32; c += gridDim.x) {
    int row = c * 32 + nl;
    const float4* F = (const float4*)&feat[(size_t)row * FEATD];
    float acc[8] = {0, 0, 0, 0, 0, 0, 0, 0};
    #pragma unroll 4
    for (int k4 = 0; k4 < 32; ++k4) {
      float4 f = F[k4];
      if (doF16 && (k4 >> 2) == slice) {
        __half2 a01 = __floats2half2_rn(f.x, f.y);
        __half2 a23 = __floats2half2_rn(f.z, f.w);
        uint2 pk;
        pk.x = *(const unsigned*)&a01;
        pk.y = *(const unsigned*)&a23;
        *(uint2*)((char*)f16 + (size_t)row * 256 + (size_t)k4 * 8) = pk;
      }
      #pragma unroll
      for (int kk = 0; kk < 4; ++kk) {
        int k = 4 * k4 + kk;
        float fv = (kk == 0) ? f.x : (kk == 1) ? f.y : (kk == 2) ? f.z : f.w;
        float4 w0 = *(const float4*)&sW[k * 64 + jg];
        float4 w1 = *(const float4*)&sW[k * 64 + jg + 4];
        acc[0] += fv * w0.x; acc[1] += fv * w0.y; acc[2] += fv * w0.z; acc[3] += fv * w0.w;
        acc[4] += fv * w1.x; acc[5] += fv * w1.y; acc[6] += fv * w1.z; acc[7] += fv * w1.w;
      }
    }
    *(float4*)&P[(size_t)row * 64 + jg]     = make_float4(acc[0], acc[1], acc[2], acc[3]);
    *(float4*)&P[(size_t)row * 64 + jg + 4] = make_float4(acc[4], acc[5], acc[6], acc[7]);
  }
}

// ---------------- fused edge kernel: coop gather (16 lanes/edge) + per-thread MLP tail ---------
// Phase 1: 16-lane groups load rows (fp16 or f32) + P slices, compute dist + h1[2/lane],
//          stash h1 in LDS tile (stride 34 to dodge bank conflicts).
// Phase 2: thread-per-edge reads its h1 row, runs W2/W3 tail with broadcast LDS weights.
template <bool F16>
__global__ __launch_bounds__(256, 4) void edge_fused(const float* __restrict__ feat,
                                                     const __half* __restrict__ feat16,
                                                     const float* __restrict__ ws,
                                                     const float* __restrict__ b1,
                                                     const float* __restrict__ b2,
                                                     const float* __restrict__ b3,
                                                     const int* __restrict__ bids,
                                                     const int* __restrict__ srcs,
                                                     const int* __restrict__ tgts,
                                                     float* __restrict__ out, int E) {
  __shared__ float sW2[1024];
  __shared__ float sW3[32], sW1l[32], sB1[32], sB2[32];
  __shared__ float ht[256 * 34];   // h1 tile, padded stride
  int tid = threadIdx.x;
  for (int i = tid; i < 1024; i += 256) sW2[i] = ws[OFF_W2 + i];
  if (tid < 32) {
    sW3[tid]  = ws[OFF_W3 + tid];
    sW1l[tid] = ws[OFF_W1L + tid];
    sB1[tid]  = b1[tid];
    sB2[tid]  = b2[tid];
  }
  __syncthreads();
  float bias3 = b3[0];
  const float* P = ws + OFF_P;
  int lane = tid & 15;   // lane within 16-lane group
  int grp  = tid >> 4;   // 0..15 groups per block

  for (int base = blockIdx.x * 256; base < E; base += gridDim.x * 256) {
    // ---- phase 1: cooperative gather, one edge per 16-lane group per round ----
    #pragma unroll 2
    for (int r = 0; r < 16; ++r) {
      int el = r * 16 + grp;
      int e  = base + el;
      if (e < E) {
        int b = bids[e], s = srcs[e], t = tgts[e];
        int rs = b * NNODES + s;
        int rt = b * NNODES + t;
        float ssd = 0.f;
        if (F16) {
          float4 av = *(const float4*)((const char*)feat16 + (size_t)rs * 256 + (size_t)lane * 16);
          float4 bv = *(const float4*)((const char*)feat16 + (size_t)rt * 256 + (size_t)lane * 16);
          const __half2* ah = (const __half2*)&av;
          const __half2* bh = (const __half2*)&bv;
          #pragma unroll
          for (int p = 0; p < 4; ++p) {
            float2 af = __half22float2(ah[p]);
            float2 bf = __half22float2(bh[p]);
            float dx = af.x - bf.x, dy = af.y - bf.y;
            ssd += dx * dx + dy * dy;
          }
        } else {
          const float4* A  = (const float4*)&feat[(size_t)rs * FEATD];
          const float4* Bp = (const float4*)&feat[(size_t)rt * FEATD];
          #pragma unroll
          for (int p = 0; p < 2; ++p) {
            float4 a = A[lane * 2 + p], c = Bp[lane * 2 + p];
            float dx = a.x - c.x, dy = a.y - c.y, dz = a.z - c.z, dw = a.w - c.w;
            ssd += dx * dx + dy * dy + dz * dz + dw * dw;
          }
        }
        ssd += __shfl_xor(ssd, 1, 64);
        ssd += __shfl_xor(ssd, 2, 64);
        ssd += __shfl_xor(ssd, 4, 64);
        ssd += __shfl_xor(ssd, 8, 64);
        float dist = sqrtf(ssd);
        float2 ps = *(const float2*)&P[(size_t)rs * 64 + 2 * lane];
        float2 pt = *(const float2*)&P[(size_t)rt * 64 + 32 + 2 * lane];
        int j0 = 2 * lane;
        float h0 = fmaxf(ps.x + pt.x + dist * sW1l[j0]     + sB1[j0],     0.f);
        float h1v = fmaxf(ps.y + pt.y + dist * sW1l[j0 + 1] + sB1[j0 + 1], 0.f);
        *(float2*)&ht[el * 34 + j0] = make_float2(h0, h1v);
      }
    }
    __syncthreads();

    // ---- phase 2: one thread per edge, MLP tail from LDS ----
    int e = base + tid;
    if (e < E) {
      float h1[32];
      #pragma unroll
      for (int q = 0; q < 16; ++q) {
        float2 v = *(const float2*)&ht[tid * 34 + 2 * q];
        h1[2 * q] = v.x; h1[2 * q + 1] = v.y;
      }
      float la = bias3;
      #pragma unroll
      for (int j = 0; j < 32; ++j) {
        float acc = sB2[j];
        #pragma unroll
        for (int q2 = 0; q2 < 8; ++q2) {
          float4 w = *(const float4*)&sW2[j * 32 + 4 * q2];
          acc += w.x * h1[4 * q2] + w.y * h1[4 * q2 + 1] + w.z * h1[4 * q2 + 2] + w.w * h1[4 * q2 + 3];
        }
        la += sW3[j] * fmaxf(acc, 0.f);
      }
      la = fminf(fmaxf(la, -5.f), 5.f);
      out[e]     = 1.0f / (1.0f + __expf(-la / 0.66f));
      out[E + e] = la;
    }
    __syncthreads();   // protect ht before next tile's phase 1
  }
}

// ---------------- fallback: no P array (tiny ws) — W1 applied in-loop, thread/edge -------------
__global__ __launch_bounds__(256) void edge_kernel_nop(const float* __restrict__ feat,
                                                       const float* __restrict__ ws,
                                                       const float* __restrict__ b1,
                                                       const float* __restrict__ b2,
                                                       const float* __restrict__ b3,
                                                       const int* __restrict__ bids,
                                                       const int* __restrict__ srcs,
                                                       const int* __restrict__ tgts,
                                                       float* __restrict__ out, int E) {
  __shared__ float sWt[128 * 64];
  __shared__ float sW2[1024];
  __shared__ float sW3[32], sW1l[32], sB1[32], sB2[32];
  int tid = threadIdx.x;
  for (int i = tid * 4; i < 128 * 64; i += 256 * 4)
    *(float4*)&sWt[i] = *(const float4*)&ws[OFF_WT + i];
  for (int i = tid; i < 1024; i += 256) sW2[i] = ws[OFF_W2 + i];
  if (tid < 32) {
    sW3[tid]  = ws[OFF_W3 + tid];
    sW1l[tid] = ws[OFF_W1L + tid];
    sB1[tid]  = b1[tid];
    sB2[tid]  = b2[tid];
  }
  __syncthreads();
  float bias3 = b3[0];

  for (int e = blockIdx.x * 256 + tid; e < E; e += gridDim.x * 256) {
    int b = bids[e], s = srcs[e], t = tgts[e];
    const float4* A  = (const float4*)&feat[(size_t)(b * NNODES + s) * FEATD];
    const float4* Bp = (const float4*)&feat[(size_t)(b * NNODES + t) * FEATD];
    float ssd = 0.f;
    float h1p[32];
    #pragma unroll
    for (int j = 0; j < 32; ++j) h1p[j] = 0.f;
    #pragma unroll 1
    for (int k4 = 0; k4 < 32; ++k4) {
      float4 a = A[k4], c = Bp[k4];
      float dx = a.x - c.x, dy = a.y - c.y, dz = a.z - c.z, dw = a.w - c.w;
      ssd += dx * dx + dy * dy + dz * dz + dw * dw;
      #pragma unroll
      for (int kk = 0; kk < 4; ++kk) {
        int k = 4 * k4 + kk;
        float fa = (kk == 0) ? a.x : (kk == 1) ? a.y : (kk == 2) ? a.z : a.w;
        float fc = (kk == 0) ? c.x : (kk == 1) ? c.y : (kk == 2) ? c.z : c.w;
        #pragma unroll
        for (int q = 0; q < 8; ++q) {
          float4 w0 = *(const float4*)&sWt[k * 64 + 4 * q];
          float4 w1 = *(const float4*)&sWt[k * 64 + 32 + 4 * q];
          h1p[4*q+0] += fa * w0.x + fc * w1.x;
          h1p[4*q+1] += fa * w0.y + fc * w1.y;
          h1p[4*q+2] += fa * w0.z + fc * w1.z;
          h1p[4*q+3] += fa * w0.w + fc * w1.w;
        }
      }
    }
    float dist = sqrtf(ssd);
    float h1[32];
    #pragma unroll
    for (int j = 0; j < 32; ++j)
      h1[j] = fmaxf(h1p[j] + dist * sW1l[j] + sB1[j], 0.f);
    float la = bias3;
    #pragma unroll
    for (int j = 0; j < 32; ++j) {
      float acc = sB2[j];
      #pragma unroll
      for (int q = 0; q < 8; ++q) {
        float4 w = *(const float4*)&sW2[j * 32 + 4 * q];
        acc += w.x * h1[4 * q] + w.y * h1[4 * q + 1] + w.z * h1[4 * q + 2] + w.w * h1[4 * q + 3];
      }
      la += sW3[j] * fmaxf(acc, 0.f);
    }
    la = fminf(fmaxf(la, -5.f), 5.f);
    out[e]     = 1.0f / (1.0f + __expf(-la / 0.66f));
    out[E + e] = la;
  }
}

extern "C" void kernel_launch(void* const* d_in, const int* in_sizes, int n_in,
                              void* d_out, int out_size, void* d_ws, size_t ws_size,
                              hipStream_t stream) {
  const float* feat = (const float*)d_in[0];
  const float* W1   = (const float*)d_in[1];
  const float* b1   = (const float*)d_in[2];
  const float* W2   = (const float*)d_in[3];
  const float* b2   = (const float*)d_in[4];
  const float* W3   = (const float*)d_in[5];
  const float* b3   = (const float*)d_in[6];
  const int* bids   = (const int*)d_in[7];
  const int* srcs   = (const int*)d_in[8];
  const int* tgts   = (const int*)d_in[9];
  float* out = (float*)d_out;
  float* ws  = (float*)d_ws;
  __half* f16 = (__half*)(ws + OFF_F16);
  int E = in_sizes[7];

  size_t need_p   = (size_t)(OFF_P + P_FLOATS) * sizeof(float);
  size_t need_f16 = need_p + (size_t)NBATCH * NNODES * FEATD * sizeof(__half);
  int egrid = (E + 255) / 256;

  spectral_kernel<<<dim3(1), dim3(256), 0, stream>>>(W1, W2, W3, ws);

  if (ws_size >= need_f16) {
    project_kernel<<<dim3(625), dim3(256), 0, stream>>>(feat, ws, f16, 1);
    edge_fused<true><<<dim3(egrid), dim3(256), 0, stream>>>(feat, f16, ws, b1, b2, b3,
                                                            bids, srcs, tgts, out, E);
  } else if (ws_size >= need_p) {
    project_kernel<<<dim3(625), dim3(256), 0, stream>>>(feat, ws, f16, 0);
    edge_fused<false><<<dim3(egrid), dim3(256), 0, stream>>>(feat, f16, ws, b1, b2, b3,
                                                             bids, srcs, tgts, out, E);
  } else {
    edge_kernel_nop<<<dim3(egrid), dim3(256), 0, stream>>>(feat, ws, b1, b2, b3,
                                                           bids, srcs, tgts, out, E);
  }
}

// Round 3
// 143.584 us; speedup vs baseline: 2.2425x; 1.2701x over previous
//
#include <hip/hip_runtime.h>
#include <hip/hip_fp16.h>
#include <math.h>

#define FEATD 128
#define NNODES 10000
#define NBATCH 4

// ws layout (float units)
#define OFF_I1  0                   // 1/sigma1
#define OFF_W1L 8                   // w1last normalized [32]
#define OFF_W2  64                  // W2 normalized [32*32]
#define OFF_W3  1088                // W3 normalized [32]
#define OFF_P   1152                // P raw [40000][64] (src-proj 0:32, tgt-proj 32:64)
#define P_FLOATS (NBATCH*NNODES*64) // 2,560,000
#define OFF_F16 (OFF_P + P_FLOATS)  // feat16[40000][128] __half (10.24 MB)
#define OFF_FBWT OFF_P              // fallback: normalized Wt[128][64] (reuses P region)

// ---------------- block-wide sum (256 threads, wave=64) ----------------
__device__ __forceinline__ float block_sum(float val, volatile float* red) {
  #pragma unroll
  for (int off = 1; off < 64; off <<= 1) val += __shfl_xor(val, off, 64);
  int tid = threadIdx.x;
  if ((tid & 63) == 0) red[tid >> 6] = val;
  __syncthreads();
  if (tid == 0) {
    float t = red[0] + red[1] + red[2] + red[3];
    red[0] = t;
  }
  __syncthreads();
  float t = red[0];
  __syncthreads();
  return t;
}

// ------------- spectral sigma, compile-time shapes, latency-parallel -------------
// Leaves raw W in sW and final v in v[]; returns sigma.
template <int M, int K>
__device__ float spectral_sigma_t(const float* __restrict__ Wg,
                                  float* sW, float* u, float* v, volatile float* red) {
  int tid = threadIdx.x;
  for (int i = tid; i < M * K; i += 256) sW[i] = Wg[i];
  if (tid < M) u[tid] = 1.0f / sqrtf((float)M);
  __syncthreads();

  int j8 = tid >> 3, l8 = tid & 7;

  for (int it = 0; it < 5; ++it) {
    // v = W^T u  (thread per k, M-unrolled)
    for (int k = tid; k < K; k += 256) {
      float a = 0.f;
      #pragma unroll
      for (int j = 0; j < M; ++j) a += sW[j * K + k] * u[j];
      v[k] = a;
    }
    __syncthreads();
    float p = 0.f;
    for (int k = tid; k < K; k += 256) p += v[k] * v[k];
    p = block_sum(p, red);
    float invv = 1.0f / (sqrtf(p) + 1e-12f);
    for (int k = tid; k < K; k += 256) v[k] *= invv;
    __syncthreads();
    // u = W v  (8 lanes per row j, K-unrolled, shfl reduce)
    float a = 0.f;
    if (j8 < M) {
      #pragma unroll
      for (int k = l8; k < K; k += 8) a += sW[j8 * K + k] * v[k];
    }
    a += __shfl_xor(a, 1, 64);
    a += __shfl_xor(a, 2, 64);
    a += __shfl_xor(a, 4, 64);
    if (j8 < M && l8 == 0) u[j8] = a;
    __syncthreads();
    float q = (tid < M) ? u[tid] * u[tid] : 0.f;
    q = block_sum(q, red);
    float invu = 1.0f / (sqrtf(q) + 1e-12f);
    if (tid < M) u[tid] *= invu;
    __syncthreads();
  }
  // sigma = u . (W v)
  float a = 0.f;
  if (j8 < M) {
    #pragma unroll
    for (int k = l8; k < K; k += 8) a += sW[j8 * K + k] * v[k];
  }
  a += __shfl_xor(a, 1, 64);
  a += __shfl_xor(a, 2, 64);
  a += __shfl_xor(a, 4, 64);
  float s = (j8 < M && l8 == 0) ? a * u[j8] : 0.f;
  s = block_sum(s, red);
  return s;
}

// ---------------- fused prep kernel ----------------
// block 0:      spectral norm of W1/W2/W3 -> ws (i1, w1l_n, W2n, W3n)
// blocks 1..N:  P_raw projection with RAW W1 (+ optional fp16 feat copy)
__global__ __launch_bounds__(256) void prep_kernel(const float* __restrict__ feat,
                                                   const float* __restrict__ W1,
                                                   const float* __restrict__ W2,
                                                   const float* __restrict__ W3,
                                                   float* __restrict__ ws,
                                                   __half* __restrict__ f16,
                                                   int doF16) {
  __shared__ float sA[32 * 257];
  __shared__ float u[32], v[257];
  __shared__ float red[8];
  int tid = threadIdx.x;

  if (blockIdx.x == 0) {
    // ---- spectral path ----
    float sig1 = spectral_sigma_t<32, 257>(W1, sA, u, v, red);
    float i1 = 1.0f / sig1;
    if (tid == 0) ws[OFF_I1] = i1;
    for (int j = tid; j < 32; j += 256) ws[OFF_W1L + j] = sA[j * 257 + 256] * i1;
    __syncthreads();
    float sig2 = spectral_sigma_t<32, 32>(W2, sA, u, v, red);
    float i2 = 1.0f / sig2;
    for (int idx = tid; idx < 1024; idx += 256) ws[OFF_W2 + idx] = sA[idx] * i2;
    __syncthreads();
    float sig3 = spectral_sigma_t<1, 32>(W3, sA, u, v, red);
    float i3 = 1.0f / sig3;
    for (int k = tid; k < 32; k += 256) ws[OFF_W3 + k] = sA[k] * i3;
    return;
  }

  // ---- projection path: stage RAW W1 transposed: sA[k*64+j] = W1[j][k], sA[k*64+32+j] = W1[j][128+k]
  for (int idx = tid; idx < 32 * 257; idx += 256) {
    int j = idx / 257, c = idx - j * 257;
    float w = W1[idx];
    if (c < 128) sA[c * 64 + j] = w;
    else if (c < 256) sA[(c - 128) * 64 + 32 + j] = w;
  }
  __syncthreads();

  float* P = ws + OFF_P;
  int nl = tid >> 3;            // node within chunk
  int jg = (tid & 7) << 3;      // output group
  int slice = (tid & 7);        // k4 slice owner for f16 write
  for (int c = blockIdx.x - 1; c < (NBATCH * NNODES) / 32; c += gridDim.x - 1) {
    int row = c * 32 + nl;
    const float4* F = (const float4*)&feat[(size_t)row * FEATD];
    float acc[8] = {0, 0, 0, 0, 0, 0, 0, 0};
    #pragma unroll 4
    for (int k4 = 0; k4 < 32; ++k4) {
      float4 f = F[k4];
      if (doF16 && (k4 >> 2) == slice) {
        __half2 a01 = __floats2half2_rn(f.x, f.y);
        __half2 a23 = __floats2half2_rn(f.z, f.w);
        uint2 pk;
        pk.x = *(const unsigned*)&a01;
        pk.y = *(const unsigned*)&a23;
        *(uint2*)((char*)f16 + (size_t)row * 256 + (size_t)k4 * 8) = pk;
      }
      #pragma unroll
      for (int kk = 0; kk < 4; ++kk) {
        int k = 4 * k4 + kk;
        float fv = (kk == 0) ? f.x : (kk == 1) ? f.y : (kk == 2) ? f.z : f.w;
        float4 w0 = *(const float4*)&sA[k * 64 + jg];
        float4 w1 = *(const float4*)&sA[k * 64 + jg + 4];
        acc[0] += fv * w0.x; acc[1] += fv * w0.y; acc[2] += fv * w0.z; acc[3] += fv * w0.w;
        acc[4] += fv * w1.x; acc[5] += fv * w1.y; acc[6] += fv * w1.z; acc[7] += fv * w1.w;
      }
    }
    *(float4*)&P[(size_t)row * 64 + jg]     = make_float4(acc[0], acc[1], acc[2], acc[3]);
    *(float4*)&P[(size_t)row * 64 + jg + 4] = make_float4(acc[4], acc[5], acc[6], acc[7]);
  }
}

// ---------------- fused edge kernel: coop gather (16 lanes/edge) + per-thread MLP tail ---------
template <bool F16>
__global__ __launch_bounds__(256, 4) void edge_fused(const float* __restrict__ feat,
                                                     const __half* __restrict__ feat16,
                                                     const float* __restrict__ ws,
                                                     const float* __restrict__ b1,
                                                     const float* __restrict__ b2,
                                                     const float* __restrict__ b3,
                                                     const int* __restrict__ bids,
                                                     const int* __restrict__ srcs,
                                                     const int* __restrict__ tgts,
                                                     float* __restrict__ out, int E) {
  __shared__ float sW2[1024];
  __shared__ float sW3[32], sW1l[32], sB1[32], sB2[32];
  __shared__ float ht[256 * 34];   // h1 tile, padded stride
  int tid = threadIdx.x;
  for (int i = tid; i < 1024; i += 256) sW2[i] = ws[OFF_W2 + i];
  if (tid < 32) {
    sW3[tid]  = ws[OFF_W3 + tid];
    sW1l[tid] = ws[OFF_W1L + tid];
    sB1[tid]  = b1[tid];
    sB2[tid]  = b2[tid];
  }
  __syncthreads();
  float bias3 = b3[0];
  float i1 = ws[OFF_I1];
  const float* P = ws + OFF_P;
  int lane = tid & 15;
  int grp  = tid >> 4;

  for (int base = blockIdx.x * 256; base < E; base += gridDim.x * 256) {
    // ---- phase 1: cooperative gather, one edge per 16-lane group per round ----
    #pragma unroll 2
    for (int r = 0; r < 16; ++r) {
      int el = r * 16 + grp;
      int e  = base + el;
      if (e < E) {
        int b = bids[e], s = srcs[e], t = tgts[e];
        int rs = b * NNODES + s;
        int rt = b * NNODES + t;
        float ssd = 0.f;
        if (F16) {
          float4 av = *(const float4*)((const char*)feat16 + (size_t)rs * 256 + (size_t)lane * 16);
          float4 bv = *(const float4*)((const char*)feat16 + (size_t)rt * 256 + (size_t)lane * 16);
          const __half2* ah = (const __half2*)&av;
          const __half2* bh = (const __half2*)&bv;
          #pragma unroll
          for (int p = 0; p < 4; ++p) {
            float2 af = __half22float2(ah[p]);
            float2 bf = __half22float2(bh[p]);
            float dx = af.x - bf.x, dy = af.y - bf.y;
            ssd += dx * dx + dy * dy;
          }
        } else {
          const float4* A  = (const float4*)&feat[(size_t)rs * FEATD];
          const float4* Bp = (const float4*)&feat[(size_t)rt * FEATD];
          #pragma unroll
          for (int p = 0; p < 2; ++p) {
            float4 a = A[lane * 2 + p], c = Bp[lane * 2 + p];
            float dx = a.x - c.x, dy = a.y - c.y, dz = a.z - c.z, dw = a.w - c.w;
            ssd += dx * dx + dy * dy + dz * dz + dw * dw;
          }
        }
        ssd += __shfl_xor(ssd, 1, 64);
        ssd += __shfl_xor(ssd, 2, 64);
        ssd += __shfl_xor(ssd, 4, 64);
        ssd += __shfl_xor(ssd, 8, 64);
        float dist = sqrtf(ssd);
        float2 ps = *(const float2*)&P[(size_t)rs * 64 + 2 * lane];
        float2 pt = *(const float2*)&P[(size_t)rt * 64 + 32 + 2 * lane];
        int j0 = 2 * lane;
        float h0  = fmaxf(fmaf(ps.x + pt.x, i1, fmaf(dist, sW1l[j0],     sB1[j0])),     0.f);
        float h1v = fmaxf(fmaf(ps.y + pt.y, i1, fmaf(dist, sW1l[j0 + 1], sB1[j0 + 1])), 0.f);
        *(float2*)&ht[el * 34 + j0] = make_float2(h0, h1v);
      }
    }
    __syncthreads();

    // ---- phase 2: one thread per edge, MLP tail from LDS ----
    int e = base + tid;
    if (e < E) {
      float h1[32];
      #pragma unroll
      for (int q = 0; q < 16; ++q) {
        float2 vv = *(const float2*)&ht[tid * 34 + 2 * q];
        h1[2 * q] = vv.x; h1[2 * q + 1] = vv.y;
      }
      float la = bias3;
      #pragma unroll
      for (int j = 0; j < 32; ++j) {
        float acc = sB2[j];
        #pragma unroll
        for (int q2 = 0; q2 < 8; ++q2) {
          float4 w = *(const float4*)&sW2[j * 32 + 4 * q2];
          acc += w.x * h1[4 * q2] + w.y * h1[4 * q2 + 1] + w.z * h1[4 * q2 + 2] + w.w * h1[4 * q2 + 3];
        }
        la += sW3[j] * fmaxf(acc, 0.f);
      }
      la = fminf(fmaxf(la, -5.f), 5.f);
      out[e]     = 1.0f / (1.0f + __expf(-la / 0.66f));
      out[E + e] = la;
    }
    __syncthreads();
  }
}

// ---------------- fallback path (tiny ws): full spectral + in-loop W1 ----------------
__global__ __launch_bounds__(256) void spectral_full(const float* __restrict__ W1,
                                                     const float* __restrict__ W2,
                                                     const float* __restrict__ W3,
                                                     float* __restrict__ ws) {
  __shared__ float sA[32 * 257];
  __shared__ float u[32], v[257];
  __shared__ float red[8];
  int tid = threadIdx.x;
  float sig1 = spectral_sigma_t<32, 257>(W1, sA, u, v, red);
  float i1 = 1.0f / sig1;
  for (int idx = tid; idx < 128 * 64; idx += 256) {
    int k = idx >> 6, jj = idx & 63;
    float w = (jj < 32) ? sA[jj * 257 + k] : sA[(jj - 32) * 257 + 128 + k];
    ws[OFF_FBWT + idx] = w * i1;
  }
  for (int j = tid; j < 32; j += 256) ws[OFF_W1L + j] = sA[j * 257 + 256] * i1;
  __syncthreads();
  float sig2 = spectral_sigma_t<32, 32>(W2, sA, u, v, red);
  float i2 = 1.0f / sig2;
  for (int idx = tid; idx < 1024; idx += 256) ws[OFF_W2 + idx] = sA[idx] * i2;
  __syncthreads();
  float sig3 = spectral_sigma_t<1, 32>(W3, sA, u, v, red);
  float i3 = 1.0f / sig3;
  for (int k = tid; k < 32; k += 256) ws[OFF_W3 + k] = sA[k] * i3;
}

__global__ __launch_bounds__(256) void edge_kernel_nop(const float* __restrict__ feat,
                                                       const float* __restrict__ ws,
                                                       const float* __restrict__ b1,
                                                       const float* __restrict__ b2,
                                                       const float* __restrict__ b3,
                                                       const int* __restrict__ bids,
                                                       const int* __restrict__ srcs,
                                                       const int* __restrict__ tgts,
                                                       float* __restrict__ out, int E) {
  __shared__ float sWt[128 * 64];
  __shared__ float sW2[1024];
  __shared__ float sW3[32], sW1l[32], sB1[32], sB2[32];
  int tid = threadIdx.x;
  for (int i = tid * 4; i < 128 * 64; i += 256 * 4)
    *(float4*)&sWt[i] = *(const float4*)&ws[OFF_FBWT + i];
  for (int i = tid; i < 1024; i += 256) sW2[i] = ws[OFF_W2 + i];
  if (tid < 32) {
    sW3[tid]  = ws[OFF_W3 + tid];
    sW1l[tid] = ws[OFF_W1L + tid];
    sB1[tid]  = b1[tid];
    sB2[tid]  = b2[tid];
  }
  __syncthreads();
  float bias3 = b3[0];

  for (int e = blockIdx.x * 256 + tid; e < E; e += gridDim.x * 256) {
    int b = bids[e], s = srcs[e], t = tgts[e];
    const float4* A  = (const float4*)&feat[(size_t)(b * NNODES + s) * FEATD];
    const float4* Bp = (const float4*)&feat[(size_t)(b * NNODES + t) * FEATD];
    float ssd = 0.f;
    float h1p[32];
    #pragma unroll
    for (int j = 0; j < 32; ++j) h1p[j] = 0.f;
    #pragma unroll 1
    for (int k4 = 0; k4 < 32; ++k4) {
      float4 a = A[k4], c = Bp[k4];
      float dx = a.x - c.x, dy = a.y - c.y, dz = a.z - c.z, dw = a.w - c.w;
      ssd += dx * dx + dy * dy + dz * dz + dw * dw;
      #pragma unroll
      for (int kk = 0; kk < 4; ++kk) {
        int k = 4 * k4 + kk;
        float fa = (kk == 0) ? a.x : (kk == 1) ? a.y : (kk == 2) ? a.z : a.w;
        float fc = (kk == 0) ? c.x : (kk == 1) ? c.y : (kk == 2) ? c.z : c.w;
        #pragma unroll
        for (int q = 0; q < 8; ++q) {
          float4 w0 = *(const float4*)&sWt[k * 64 + 4 * q];
          float4 w1 = *(const float4*)&sWt[k * 64 + 32 + 4 * q];
          h1p[4*q+0] += fa * w0.x + fc * w1.x;
          h1p[4*q+1] += fa * w0.y + fc * w1.y;
          h1p[4*q+2] += fa * w0.z + fc * w1.z;
          h1p[4*q+3] += fa * w0.w + fc * w1.w;
        }
      }
    }
    float dist = sqrtf(ssd);
    float h1[32];
    #pragma unroll
    for (int j = 0; j < 32; ++j)
      h1[j] = fmaxf(h1p[j] + dist * sW1l[j] + sB1[j], 0.f);
    float la = bias3;
    #pragma unroll
    for (int j = 0; j < 32; ++j) {
      float acc = sB2[j];
      #pragma unroll
      for (int q = 0; q < 8; ++q) {
        float4 w = *(const float4*)&sW2[j * 32 + 4 * q];
        acc += w.x * h1[4 * q] + w.y * h1[4 * q + 1] + w.z * h1[4 * q + 2] + w.w * h1[4 * q + 3];
      }
      la += sW3[j] * fmaxf(acc, 0.f);
    }
    la = fminf(fmaxf(la, -5.f), 5.f);
    out[e]     = 1.0f / (1.0f + __expf(-la / 0.66f));
    out[E + e] = la;
  }
}

extern "C" void kernel_launch(void* const* d_in, const int* in_sizes, int n_in,
                              void* d_out, int out_size, void* d_ws, size_t ws_size,
                              hipStream_t stream) {
  const float* feat = (const float*)d_in[0];
  const float* W1   = (const float*)d_in[1];
  const float* b1   = (const float*)d_in[2];
  const float* W2   = (const float*)d_in[3];
  const float* b2   = (const float*)d_in[4];
  const float* W3   = (const float*)d_in[5];
  const float* b3   = (const float*)d_in[6];
  const int* bids   = (const int*)d_in[7];
  const int* srcs   = (const int*)d_in[8];
  const int* tgts   = (const int*)d_in[9];
  float* out = (float*)d_out;
  float* ws  = (float*)d_ws;
  __half* f16 = (__half*)(ws + OFF_F16);
  int E = in_sizes[7];

  size_t need_p   = (size_t)OFF_F16 * sizeof(float);
  size_t need_f16 = need_p + (size_t)NBATCH * NNODES * FEATD * sizeof(__half);
  int egrid = (E + 255) / 256;

  if (ws_size >= need_f16) {
    prep_kernel<<<dim3(1251), dim3(256), 0, stream>>>(feat, W1, W2, W3, ws, f16, 1);
    edge_fused<true><<<dim3(egrid), dim3(256), 0, stream>>>(feat, f16, ws, b1, b2, b3,
                                                            bids, srcs, tgts, out, E);
  } else if (ws_size >= need_p) {
    prep_kernel<<<dim3(1251), dim3(256), 0, stream>>>(feat, W1, W2, W3, ws, f16, 0);
    edge_fused<false><<<dim3(egrid), dim3(256), 0, stream>>>(feat, f16, ws, b1, b2, b3,
                                                             bids, srcs, tgts, out, E);
  } else {
    spectral_full<<<dim3(1), dim3(256), 0, stream>>>(W1, W2, W3, ws);
    edge_kernel_nop<<<dim3(egrid), dim3(256), 0, stream>>>(feat, ws, b1, b2, b3,
                                                           bids, srcs, tgts, out, E);
  }
}

// Round 4
// 126.042 us; speedup vs baseline: 2.5546x; 1.1392x over previous
//
#include <hip/hip_runtime.h>
#include <hip/hip_fp16.h>
#include <math.h>

#define FEATD 128
#define NNODES 10000
#define NBATCH 4
#define NROWS (NBATCH*NNODES)   // 40000

// ws layout (float units)
#define OFF_I1   0                     // 1/sigma1
#define OFF_W1L  8                     // w1last normalized [32] f32
#define OFF_W2   64                    // W2 normalized [32*32] f32 (fallback)
#define OFF_W3   1088                  // W3 normalized [32] f32
#define OFF_W2H  1120                  // W2 normalized half2 [512 uint slots]
#define OFF_P16  2048                  // P16 raw proj [40000][64] half (5.12 MB)
#define P16_FLOATS (NROWS*64/2)        // 1,280,000 float slots
#define OFF_F16  (OFF_P16 + P16_FLOATS) // feat16 [40000][128] half (10.24 MB)
#define F16_FLOATS (NROWS*FEATD/2)     // 1,280,000 float slots
#define OFF_FBWT OFF_P16               // fallback: normalized Wt[128][64] f32 (reuses P16 region)

typedef _Float16 h2 __attribute__((ext_vector_type(2)));
union U32H2 { unsigned u; h2 h; };
union U4H2  { uint4 u; h2 h[4]; };

#if defined(__has_builtin)
#if __has_builtin(__builtin_amdgcn_fdot2)
#define HAVE_FDOT2 1
#endif
#endif

__device__ __forceinline__ float fdot2f(h2 a, h2 b, float c) {
#ifdef HAVE_FDOT2
  return __builtin_amdgcn_fdot2(a, b, c, false);
#else
  return c + (float)a[0] * (float)b[0] + (float)a[1] * (float)b[1];
#endif
}

// ---------------- block-wide sum (256 threads, wave=64) ----------------
__device__ __forceinline__ float block_sum(float val, volatile float* red) {
  #pragma unroll
  for (int off = 1; off < 64; off <<= 1) val += __shfl_xor(val, off, 64);
  int tid = threadIdx.x;
  if ((tid & 63) == 0) red[tid >> 6] = val;
  __syncthreads();
  if (tid == 0) {
    float t = red[0] + red[1] + red[2] + red[3];
    red[0] = t;
  }
  __syncthreads();
  float t = red[0];
  __syncthreads();
  return t;
}

// ------------- spectral sigma, compile-time shapes, latency-parallel -------------
// Leaves raw W in sW and final v in v[]; returns sigma.
template <int M, int K>
__device__ float spectral_sigma_t(const float* __restrict__ Wg,
                                  float* sW, float* u, float* v, volatile float* red) {
  int tid = threadIdx.x;
  for (int i = tid; i < M * K; i += 256) sW[i] = Wg[i];
  if (tid < M) u[tid] = 1.0f / sqrtf((float)M);
  __syncthreads();

  int j8 = tid >> 3, l8 = tid & 7;

  for (int it = 0; it < 5; ++it) {
    for (int k = tid; k < K; k += 256) {
      float a = 0.f;
      #pragma unroll
      for (int j = 0; j < M; ++j) a += sW[j * K + k] * u[j];
      v[k] = a;
    }
    __syncthreads();
    float p = 0.f;
    for (int k = tid; k < K; k += 256) p += v[k] * v[k];
    p = block_sum(p, red);
    float invv = 1.0f / (sqrtf(p) + 1e-12f);
    for (int k = tid; k < K; k += 256) v[k] *= invv;
    __syncthreads();
    float a = 0.f;
    if (j8 < M) {
      #pragma unroll
      for (int k = l8; k < K; k += 8) a += sW[j8 * K + k] * v[k];
    }
    a += __shfl_xor(a, 1, 64);
    a += __shfl_xor(a, 2, 64);
    a += __shfl_xor(a, 4, 64);
    if (j8 < M && l8 == 0) u[j8] = a;
    __syncthreads();
    float q = (tid < M) ? u[tid] * u[tid] : 0.f;
    q = block_sum(q, red);
    float invu = 1.0f / (sqrtf(q) + 1e-12f);
    if (tid < M) u[tid] *= invu;
    __syncthreads();
  }
  float a = 0.f;
  if (j8 < M) {
    #pragma unroll
    for (int k = l8; k < K; k += 8) a += sW[j8 * K + k] * v[k];
  }
  a += __shfl_xor(a, 1, 64);
  a += __shfl_xor(a, 2, 64);
  a += __shfl_xor(a, 4, 64);
  float s = (j8 < M && l8 == 0) ? a * u[j8] : 0.f;
  s = block_sum(s, red);
  return s;
}

// ---------------- fused prep kernel ----------------
// block 0:      spectral norm -> ws (i1, w1l_n, W2n f32, W2n half2, W3n)
// blocks 1..625: P16 raw projection with RAW W1 (2 rows/thread) + optional f16 feat copy
__global__ __launch_bounds__(256) void prep_kernel(const float* __restrict__ feat,
                                                   const float* __restrict__ W1,
                                                   const float* __restrict__ W2,
                                                   const float* __restrict__ W3,
                                                   float* __restrict__ ws,
                                                   int doF16) {
  __shared__ float sA[32 * 257];
  __shared__ float u[32], v[257];
  __shared__ float red[8];
  int tid = threadIdx.x;

  if (blockIdx.x == 0) {
    float sig1 = spectral_sigma_t<32, 257>(W1, sA, u, v, red);
    float i1 = 1.0f / sig1;
    if (tid == 0) ws[OFF_I1] = i1;
    for (int j = tid; j < 32; j += 256) ws[OFF_W1L + j] = sA[j * 257 + 256] * i1;
    __syncthreads();
    float sig2 = spectral_sigma_t<32, 32>(W2, sA, u, v, red);
    float i2 = 1.0f / sig2;
    for (int idx = tid; idx < 1024; idx += 256) ws[OFF_W2 + idx] = sA[idx] * i2;
    // packed half2 copy: w2h[j*16+q] = {W2n[j][2q], W2n[j][2q+1]}
    unsigned* w2h = (unsigned*)(ws + OFF_W2H);
    for (int idx = tid; idx < 512; idx += 256) {
      int j = idx >> 4, q = idx & 15;
      U32H2 pk;
      pk.h[0] = (_Float16)(sA[j * 32 + 2 * q] * i2);
      pk.h[1] = (_Float16)(sA[j * 32 + 2 * q + 1] * i2);
      w2h[idx] = pk.u;
    }
    __syncthreads();
    float sig3 = spectral_sigma_t<1, 32>(W3, sA, u, v, red);
    float i3 = 1.0f / sig3;
    for (int k = tid; k < 32; k += 256) ws[OFF_W3 + k] = sA[k] * i3;
    return;
  }

  // projection path: stage RAW W1 transposed: sA[k*64+j] = W1[j][k], sA[k*64+32+j] = W1[j][128+k]
  for (int idx = tid; idx < 32 * 257; idx += 256) {
    int j = idx / 257, c = idx - j * 257;
    float w = W1[idx];
    if (c < 128) sA[c * 64 + j] = w;
    else if (c < 256) sA[(c - 128) * 64 + 32 + j] = w;
  }
  __syncthreads();

  __half* p16 = (__half*)(ws + OFF_P16);
  __half* f16 = (__half*)(ws + OFF_F16);
  int nl = tid >> 3;            // 0..31: row pair within chunk
  int jg = (tid & 7) << 3;      // output group (8 j's)
  int slice = (tid & 7);        // k4 slice owner for f16 write
  int c = blockIdx.x - 1;       // 0..624, 64 rows each -> exact
  int r0 = c * 64 + nl * 2;
  int r1 = r0 + 1;
  const float4* F0 = (const float4*)&feat[(size_t)r0 * FEATD];
  const float4* F1 = (const float4*)&feat[(size_t)r1 * FEATD];
  float acc0[8] = {0,0,0,0,0,0,0,0};
  float acc1[8] = {0,0,0,0,0,0,0,0};
  #pragma unroll 2
  for (int k4 = 0; k4 < 32; ++k4) {
    float4 f0 = F0[k4];
    float4 f1 = F1[k4];
    if (doF16 && (k4 >> 2) == slice) {
      U32H2 a, b;
      uint2 pk;
      a.h[0] = (_Float16)f0.x; a.h[1] = (_Float16)f0.y; pk.x = a.u;
      b.h[0] = (_Float16)f0.z; b.h[1] = (_Float16)f0.w; pk.y = b.u;
      *(uint2*)((char*)f16 + (size_t)r0 * 256 + (size_t)k4 * 8) = pk;
      a.h[0] = (_Float16)f1.x; a.h[1] = (_Float16)f1.y; pk.x = a.u;
      b.h[0] = (_Float16)f1.z; b.h[1] = (_Float16)f1.w; pk.y = b.u;
      *(uint2*)((char*)f16 + (size_t)r1 * 256 + (size_t)k4 * 8) = pk;
    }
    #pragma unroll
    for (int kk = 0; kk < 4; ++kk) {
      int k = 4 * k4 + kk;
      float fv0 = (kk == 0) ? f0.x : (kk == 1) ? f0.y : (kk == 2) ? f0.z : f0.w;
      float fv1 = (kk == 0) ? f1.x : (kk == 1) ? f1.y : (kk == 2) ? f1.z : f1.w;
      float4 w0 = *(const float4*)&sA[k * 64 + jg];
      float4 w1 = *(const float4*)&sA[k * 64 + jg + 4];
      acc0[0] += fv0 * w0.x; acc0[1] += fv0 * w0.y; acc0[2] += fv0 * w0.z; acc0[3] += fv0 * w0.w;
      acc0[4] += fv0 * w1.x; acc0[5] += fv0 * w1.y; acc0[6] += fv0 * w1.z; acc0[7] += fv0 * w1.w;
      acc1[0] += fv1 * w0.x; acc1[1] += fv1 * w0.y; acc1[2] += fv1 * w0.z; acc1[3] += fv1 * w0.w;
      acc1[4] += fv1 * w1.x; acc1[5] += fv1 * w1.y; acc1[6] += fv1 * w1.z; acc1[7] += fv1 * w1.w;
    }
  }
  // pack 8 f32 -> 4 half2 -> uint4, store 16B per row slice
  U32H2 t0, t1, t2, t3;
  uint4 o;
  t0.h[0]=(_Float16)acc0[0]; t0.h[1]=(_Float16)acc0[1];
  t1.h[0]=(_Float16)acc0[2]; t1.h[1]=(_Float16)acc0[3];
  t2.h[0]=(_Float16)acc0[4]; t2.h[1]=(_Float16)acc0[5];
  t3.h[0]=(_Float16)acc0[6]; t3.h[1]=(_Float16)acc0[7];
  o.x=t0.u; o.y=t1.u; o.z=t2.u; o.w=t3.u;
  *(uint4*)((char*)p16 + (size_t)r0 * 128 + (size_t)jg * 2) = o;
  t0.h[0]=(_Float16)acc1[0]; t0.h[1]=(_Float16)acc1[1];
  t1.h[0]=(_Float16)acc1[2]; t1.h[1]=(_Float16)acc1[3];
  t2.h[0]=(_Float16)acc1[4]; t2.h[1]=(_Float16)acc1[5];
  t3.h[0]=(_Float16)acc1[6]; t3.h[1]=(_Float16)acc1[7];
  o.x=t0.u; o.y=t1.u; o.z=t2.u; o.w=t3.u;
  *(uint4*)((char*)p16 + (size_t)r1 * 128 + (size_t)jg * 2) = o;
}

// ---------------- fused edge kernel ----------------
// Phase 1: 16-lane groups: f16 rows -> dist (pk_sub+fdot2), P16 slices -> h1 (half2) -> ht LDS.
// Phase 2: thread-per-edge tail: W2 half2 via SCALAR loads + fdot2.
template <bool F16>
__global__ __launch_bounds__(256, 8) void edge_fused(const float* __restrict__ feat,
                                                     const float* __restrict__ ws,
                                                     const float* __restrict__ b1,
                                                     const float* __restrict__ b2,
                                                     const float* __restrict__ b3,
                                                     const int* __restrict__ bids,
                                                     const int* __restrict__ srcs,
                                                     const int* __restrict__ tgts,
                                                     float* __restrict__ out, int E) {
  __shared__ unsigned ht[256 * 17];   // h1 tile as half2, padded stride
  int tid = threadIdx.x;
  int lane = tid & 15;
  int grp  = tid >> 4;

  const __half* feat16 = (const __half*)(ws + OFF_F16);
  const __half* p16    = (const __half*)(ws + OFF_P16);
  const unsigned* w2h  = (const unsigned*)(ws + OFF_W2H);

  // per-lane constants (uniform across tiles) hoisted to registers
  float i1 = ws[OFF_I1];
  int j0 = 2 * lane;
  float w1l0 = ws[OFF_W1L + j0];
  float w1l1 = ws[OFF_W1L + j0 + 1];
  float bb0  = b1[j0];
  float bb1  = b1[j0 + 1];
  float bias3 = b3[0];

  for (int base = blockIdx.x * 256; base < E; base += gridDim.x * 256) {
    // ---- phase 1 ----
    #pragma unroll 2
    for (int r = 0; r < 16; ++r) {
      int el = r * 16 + grp;
      int e  = base + el;
      if (e < E) {
        int b = bids[e], s = srcs[e], t = tgts[e];
        int rs = b * NNODES + s;
        int rt = b * NNODES + t;
        float ssd = 0.f;
        if (F16) {
          U4H2 av, bv;
          av.u = *(const uint4*)((const char*)feat16 + ((size_t)rs << 8) + (lane << 4));
          bv.u = *(const uint4*)((const char*)feat16 + ((size_t)rt << 8) + (lane << 4));
          #pragma unroll
          for (int p = 0; p < 4; ++p) {
            h2 d = av.h[p] - bv.h[p];
            ssd = fdot2f(d, d, ssd);
          }
        } else {
          const float4* A  = (const float4*)&feat[(size_t)rs * FEATD];
          const float4* Bp = (const float4*)&feat[(size_t)rt * FEATD];
          #pragma unroll
          for (int p = 0; p < 2; ++p) {
            float4 a = A[lane * 2 + p], c = Bp[lane * 2 + p];
            float dx = a.x - c.x, dy = a.y - c.y, dz = a.z - c.z, dw = a.w - c.w;
            ssd += dx * dx + dy * dy + dz * dz + dw * dw;
          }
        }
        ssd += __shfl_xor(ssd, 1, 64);
        ssd += __shfl_xor(ssd, 2, 64);
        ssd += __shfl_xor(ssd, 4, 64);
        ssd += __shfl_xor(ssd, 8, 64);
        float dist = sqrtf(ssd);
        U32H2 pu, qu;
        pu.u = *(const unsigned*)((const char*)p16 + ((size_t)rs << 7) + (lane << 2));
        qu.u = *(const unsigned*)((const char*)p16 + ((size_t)rt << 7) + 64 + (lane << 2));
        float h0  = fmaxf(fmaf((float)pu.h[0] + (float)qu.h[0], i1, fmaf(dist, w1l0, bb0)), 0.f);
        float h1v = fmaxf(fmaf((float)pu.h[1] + (float)qu.h[1], i1, fmaf(dist, w1l1, bb1)), 0.f);
        U32H2 hp;
        hp.h[0] = (_Float16)h0;
        hp.h[1] = (_Float16)h1v;
        ht[el * 17 + lane] = hp.u;
      }
    }
    __syncthreads();

    // ---- phase 2: thread-per-edge tail (W2 via scalar loads + fdot2) ----
    int e = base + tid;
    if (e < E) {
      unsigned hrow[16];
      #pragma unroll
      for (int q = 0; q < 16; ++q) hrow[q] = ht[tid * 17 + q];
      float la = bias3;
      #pragma unroll
      for (int j = 0; j < 32; ++j) {
        float acc = b2[j];
        #pragma unroll
        for (int q = 0; q < 16; ++q) {
          U32H2 w; w.u = w2h[j * 16 + q];
          U32H2 h; h.u = hrow[q];
          acc = fdot2f(w.h, h.h, acc);
        }
        la += ws[OFF_W3 + j] * fmaxf(acc, 0.f);
      }
      la = fminf(fmaxf(la, -5.f), 5.f);
      out[e]     = 1.0f / (1.0f + exp2f(la * -2.18590179f));
      out[E + e] = la;
    }
    __syncthreads();
  }
}

// ---------------- fallback path (tiny ws): full spectral + in-loop W1, all f32 ----------------
__global__ __launch_bounds__(256) void spectral_full(const float* __restrict__ W1,
                                                     const float* __restrict__ W2,
                                                     const float* __restrict__ W3,
                                                     float* __restrict__ ws) {
  __shared__ float sA[32 * 257];
  __shared__ float u[32], v[257];
  __shared__ float red[8];
  int tid = threadIdx.x;
  float sig1 = spectral_sigma_t<32, 257>(W1, sA, u, v, red);
  float i1 = 1.0f / sig1;
  for (int idx = tid; idx < 128 * 64; idx += 256) {
    int k = idx >> 6, jj = idx & 63;
    float w = (jj < 32) ? sA[jj * 257 + k] : sA[(jj - 32) * 257 + 128 + k];
    ws[OFF_FBWT + idx] = w * i1;
  }
  for (int j = tid; j < 32; j += 256) ws[OFF_W1L + j] = sA[j * 257 + 256] * i1;
  __syncthreads();
  float sig2 = spectral_sigma_t<32, 32>(W2, sA, u, v, red);
  float i2 = 1.0f / sig2;
  for (int idx = tid; idx < 1024; idx += 256) ws[OFF_W2 + idx] = sA[idx] * i2;
  __syncthreads();
  float sig3 = spectral_sigma_t<1, 32>(W3, sA, u, v, red);
  float i3 = 1.0f / sig3;
  for (int k = tid; k < 32; k += 256) ws[OFF_W3 + k] = sA[k] * i3;
}

__global__ __launch_bounds__(256) void edge_kernel_nop(const float* __restrict__ feat,
                                                       const float* __restrict__ ws,
                                                       const float* __restrict__ b1,
                                                       const float* __restrict__ b2,
                                                       const float* __restrict__ b3,
                                                       const int* __restrict__ bids,
                                                       const int* __restrict__ srcs,
                                                       const int* __restrict__ tgts,
                                                       float* __restrict__ out, int E) {
  __shared__ float sWt[128 * 64];
  __shared__ float sW2[1024];
  __shared__ float sW3[32], sW1l[32], sB1[32], sB2[32];
  int tid = threadIdx.x;
  for (int i = tid * 4; i < 128 * 64; i += 256 * 4)
    *(float4*)&sWt[i] = *(const float4*)&ws[OFF_FBWT + i];
  for (int i = tid; i < 1024; i += 256) sW2[i] = ws[OFF_W2 + i];
  if (tid < 32) {
    sW3[tid]  = ws[OFF_W3 + tid];
    sW1l[tid] = ws[OFF_W1L + tid];
    sB1[tid]  = b1[tid];
    sB2[tid]  = b2[tid];
  }
  __syncthreads();
  float bias3 = b3[0];

  for (int e = blockIdx.x * 256 + tid; e < E; e += gridDim.x * 256) {
    int b = bids[e], s = srcs[e], t = tgts[e];
    const float4* A  = (const float4*)&feat[(size_t)(b * NNODES + s) * FEATD];
    const float4* Bp = (const float4*)&feat[(size_t)(b * NNODES + t) * FEATD];
    float ssd = 0.f;
    float h1p[32];
    #pragma unroll
    for (int j = 0; j < 32; ++j) h1p[j] = 0.f;
    #pragma unroll 1
    for (int k4 = 0; k4 < 32; ++k4) {
      float4 a = A[k4], c = Bp[k4];
      float dx = a.x - c.x, dy = a.y - c.y, dz = a.z - c.z, dw = a.w - c.w;
      ssd += dx * dx + dy * dy + dz * dz + dw * dw;
      #pragma unroll
      for (int kk = 0; kk < 4; ++kk) {
        int k = 4 * k4 + kk;
        float fa = (kk == 0) ? a.x : (kk == 1) ? a.y : (kk == 2) ? a.z : a.w;
        float fc = (kk == 0) ? c.x : (kk == 1) ? c.y : (kk == 2) ? c.z : c.w;
        #pragma unroll
        for (int q = 0; q < 8; ++q) {
          float4 w0 = *(const float4*)&sWt[k * 64 + 4 * q];
          float4 w1 = *(const float4*)&sWt[k * 64 + 32 + 4 * q];
          h1p[4*q+0] += fa * w0.x + fc * w1.x;
          h1p[4*q+1] += fa * w0.y + fc * w1.y;
          h1p[4*q+2] += fa * w0.z + fc * w1.z;
          h1p[4*q+3] += fa * w0.w + fc * w1.w;
        }
      }
    }
    float dist = sqrtf(ssd);
    float h1[32];
    #pragma unroll
    for (int j = 0; j < 32; ++j)
      h1[j] = fmaxf(h1p[j] + dist * sW1l[j] + sB1[j], 0.f);
    float la = bias3;
    #pragma unroll
    for (int j = 0; j < 32; ++j) {
      float acc = sB2[j];
      #pragma unroll
      for (int q = 0; q < 8; ++q) {
        float4 w = *(const float4*)&sW2[j * 32 + 4 * q];
        acc += w.x * h1[4 * q] + w.y * h1[4 * q + 1] + w.z * h1[4 * q + 2] + w.w * h1[4 * q + 3];
      }
      la += sW3[j] * fmaxf(acc, 0.f);
    }
    la = fminf(fmaxf(la, -5.f), 5.f);
    out[e]     = 1.0f / (1.0f + __expf(-la / 0.66f));
    out[E + e] = la;
  }
}

extern "C" void kernel_launch(void* const* d_in, const int* in_sizes, int n_in,
                              void* d_out, int out_size, void* d_ws, size_t ws_size,
                              hipStream_t stream) {
  const float* feat = (const float*)d_in[0];
  const float* W1   = (const float*)d_in[1];
  const float* b1   = (const float*)d_in[2];
  const float* W2   = (const float*)d_in[3];
  const float* b2   = (const float*)d_in[4];
  const float* W3   = (const float*)d_in[5];
  const float* b3   = (const float*)d_in[6];
  const int* bids   = (const int*)d_in[7];
  const int* srcs   = (const int*)d_in[8];
  const int* tgts   = (const int*)d_in[9];
  float* out = (float*)d_out;
  float* ws  = (float*)d_ws;
  int E = in_sizes[7];

  size_t need_p   = (size_t)OFF_F16 * sizeof(float);                       // P16 only
  size_t need_f16 = (size_t)(OFF_F16 + F16_FLOATS) * sizeof(float);        // + feat16
  int egrid = (E + 255) / 256;

  if (ws_size >= need_f16) {
    prep_kernel<<<dim3(626), dim3(256), 0, stream>>>(feat, W1, W2, W3, ws, 1);
    edge_fused<true><<<dim3(egrid), dim3(256), 0, stream>>>(feat, ws, b1, b2, b3,
                                                            bids, srcs, tgts, out, E);
  } else if (ws_size >= need_p) {
    prep_kernel<<<dim3(626), dim3(256), 0, stream>>>(feat, W1, W2, W3, ws, 0);
    edge_fused<false><<<dim3(egrid), dim3(256), 0, stream>>>(feat, ws, b1, b2, b3,
                                                             bids, srcs, tgts, out, E);
  } else {
    spectral_full<<<dim3(1), dim3(256), 0, stream>>>(W1, W2, W3, ws);
    edge_kernel_nop<<<dim3(egrid), dim3(256), 0, stream>>>(feat, ws, b1, b2, b3,
                                                           bids, srcs, tgts, out, E);
  }
}

// Round 5
// 110.140 us; speedup vs baseline: 2.9234x; 1.1444x over previous
//
#include <hip/hip_runtime.h>
#include <hip/hip_fp16.h>
#include <math.h>

#define FEATD 128
#define NNODES 10000
#define NBATCH 4
#define NROWS (NBATCH*NNODES)   // 40000

// ws layout (float units)
#define OFF_I1   0                     // 1/sigma1
#define OFF_W1L  8                     // w1last normalized [32] f32
#define OFF_W2   64                    // W2 normalized [32*32] f32 (fallback)
#define OFF_W3   1088                  // W3 normalized [32] f32
#define OFF_W2H  1120                  // W2 normalized half2 [512 uint slots]
#define OFF_P16  2048                  // P16 raw proj [40000][64] half (5.12 MB)
#define P16_FLOATS (NROWS*64/2)        // 1,280,000 float slots
#define OFF_F16  (OFF_P16 + P16_FLOATS) // feat16 [40000][128] half (10.24 MB)
#define F16_FLOATS (NROWS*FEATD/2)     // 1,280,000 float slots
#define OFF_FBWT OFF_P16               // fallback: normalized Wt[128][64] f32 (reuses P16 region)

typedef _Float16 h2 __attribute__((ext_vector_type(2)));
union U32H2 { unsigned u; h2 h; };
union U4H2  { uint4 u; h2 h[4]; };

#if defined(__has_builtin)
#if __has_builtin(__builtin_amdgcn_fdot2)
#define HAVE_FDOT2 1
#endif
#endif

__device__ __forceinline__ float fdot2f(h2 a, h2 b, float c) {
#ifdef HAVE_FDOT2
  return __builtin_amdgcn_fdot2(a, b, c, false);
#else
  return c + (float)a[0] * (float)b[0] + (float)a[1] * (float)b[1];
#endif
}

// ------------- spectral sigma: exact reference power iteration, 2 barriers/iter -------------
// u[] holds RAW u (unnormalized); invu scalar held by all threads. v[] holds raw v.
// Leaves raw W in sW and raw v in v[]; returns sigma.
template <int M, int K>
__device__ float spectral_sigma_t(const float* __restrict__ Wg,
                                  float* sW, float* u, float* v, volatile float* red) {
  int tid = threadIdx.x;
  int wid = tid >> 6, lid = tid & 63;
  int j8 = tid >> 3, l8 = tid & 7;
  for (int i = tid; i < M * K; i += 256) sW[i] = Wg[i];
  if (tid < M) u[tid] = 1.0f;          // raw u = 1; uhat = u * invu
  __syncthreads();
  float invu = 1.0f / sqrtf((float)M);
  float invv = 0.f;

  for (int it = 0; it < 5; ++it) {
    // v = W^T uhat ; p = ||v||^2
    float p = 0.f;
    for (int k = tid; k < K; k += 256) {
      float a = 0.f;
      #pragma unroll
      for (int j = 0; j < M; ++j) a += sW[j * K + k] * u[j];
      a *= invu;
      v[k] = a;
      p += a * a;
    }
    #pragma unroll
    for (int off = 1; off < 64; off <<= 1) p += __shfl_xor(p, off, 64);
    if (lid == 0) red[wid] = p;
    __syncthreads();                       // v[] visible + red ready
    p = red[0] + red[1] + red[2] + red[3];
    invv = 1.0f / (sqrtf(p) + 1e-12f);

    // u = W vhat  (8 lanes per row j) ; q = ||u||^2
    float a = 0.f;
    if (j8 < M) {
      #pragma unroll
      for (int k = l8; k < K; k += 8) a += sW[j8 * K + k] * v[k];
      a *= invv;
    }
    a += __shfl_xor(a, 1, 64);
    a += __shfl_xor(a, 2, 64);
    a += __shfl_xor(a, 4, 64);
    float q = 0.f;
    if (j8 < M && l8 == 0) { u[j8] = a; q = a * a; }
    #pragma unroll
    for (int off = 1; off < 64; off <<= 1) q += __shfl_xor(q, off, 64);
    if (lid == 0) red[4 + wid] = q;
    __syncthreads();                       // u[] visible + red[4..7] ready
    q = red[4] + red[5] + red[6] + red[7];
    invu = 1.0f / (sqrtf(q) + 1e-12f);
  }

  // sigma = uhat . (W vhat) = invu*invv * sum_j u_raw[j] * (W v_raw)_j
  float a = 0.f;
  if (j8 < M) {
    #pragma unroll
    for (int k = l8; k < K; k += 8) a += sW[j8 * K + k] * v[k];
  }
  a += __shfl_xor(a, 1, 64);
  a += __shfl_xor(a, 2, 64);
  a += __shfl_xor(a, 4, 64);
  float s = (j8 < M && l8 == 0) ? a * u[j8] : 0.f;
  #pragma unroll
  for (int off = 1; off < 64; off <<= 1) s += __shfl_xor(s, off, 64);
  if (lid == 0) red[wid] = s;
  __syncthreads();
  float sig = (red[0] + red[1] + red[2] + red[3]) * invu * invv;
  __syncthreads();
  return sig;
}

// ---------------- fused prep kernel ----------------
// block 0:      spectral norm -> ws (i1, w1l_n, W2n f32, W2n half2, W3n)
// blocks 1..625: P16 raw projection with RAW W1 (2 rows/thread) + optional f16 feat copy
__global__ __launch_bounds__(256) void prep_kernel(const float* __restrict__ feat,
                                                   const float* __restrict__ W1,
                                                   const float* __restrict__ W2,
                                                   const float* __restrict__ W3,
                                                   float* __restrict__ ws,
                                                   int doF16) {
  __shared__ float sA[32 * 257];
  __shared__ float u[32], v[257];
  __shared__ float red[8];
  int tid = threadIdx.x;

  if (blockIdx.x == 0) {
    float sig1 = spectral_sigma_t<32, 257>(W1, sA, u, v, red);
    float i1 = 1.0f / sig1;
    if (tid == 0) ws[OFF_I1] = i1;
    for (int j = tid; j < 32; j += 256) ws[OFF_W1L + j] = sA[j * 257 + 256] * i1;
    __syncthreads();
    float sig2 = spectral_sigma_t<32, 32>(W2, sA, u, v, red);
    float i2 = 1.0f / sig2;
    for (int idx = tid; idx < 1024; idx += 256) ws[OFF_W2 + idx] = sA[idx] * i2;
    unsigned* w2h = (unsigned*)(ws + OFF_W2H);
    for (int idx = tid; idx < 512; idx += 256) {
      int j = idx >> 4, q = idx & 15;
      U32H2 pk;
      pk.h[0] = (_Float16)(sA[j * 32 + 2 * q] * i2);
      pk.h[1] = (_Float16)(sA[j * 32 + 2 * q + 1] * i2);
      w2h[idx] = pk.u;
    }
    __syncthreads();
    float sig3 = spectral_sigma_t<1, 32>(W3, sA, u, v, red);
    float i3 = 1.0f / sig3;
    for (int k = tid; k < 32; k += 256) ws[OFF_W3 + k] = sA[k] * i3;
    return;
  }

  // projection path: stage RAW W1 transposed: sA[k*64+j] = W1[j][k], sA[k*64+32+j] = W1[j][128+k]
  for (int idx = tid; idx < 32 * 257; idx += 256) {
    int j = idx / 257, c = idx - j * 257;
    float w = W1[idx];
    if (c < 128) sA[c * 64 + j] = w;
    else if (c < 256) sA[(c - 128) * 64 + 32 + j] = w;
  }
  __syncthreads();

  __half* p16 = (__half*)(ws + OFF_P16);
  __half* f16 = (__half*)(ws + OFF_F16);
  int nl = tid >> 3;            // 0..31: row pair within chunk
  int jg = (tid & 7) << 3;      // output group (8 j's)
  int slice = (tid & 7);        // k4 slice owner for f16 write
  int c = blockIdx.x - 1;       // 0..624, 64 rows each -> exact
  int r0 = c * 64 + nl * 2;
  int r1 = r0 + 1;
  const float4* F0 = (const float4*)&feat[(size_t)r0 * FEATD];
  const float4* F1 = (const float4*)&feat[(size_t)r1 * FEATD];
  float acc0[8] = {0,0,0,0,0,0,0,0};
  float acc1[8] = {0,0,0,0,0,0,0,0};
  #pragma unroll 2
  for (int k4 = 0; k4 < 32; ++k4) {
    float4 f0 = F0[k4];
    float4 f1 = F1[k4];
    if (doF16 && (k4 >> 2) == slice) {
      U32H2 a, b;
      uint2 pk;
      a.h[0] = (_Float16)f0.x; a.h[1] = (_Float16)f0.y; pk.x = a.u;
      b.h[0] = (_Float16)f0.z; b.h[1] = (_Float16)f0.w; pk.y = b.u;
      *(uint2*)((char*)f16 + (size_t)r0 * 256 + (size_t)k4 * 8) = pk;
      a.h[0] = (_Float16)f1.x; a.h[1] = (_Float16)f1.y; pk.x = a.u;
      b.h[0] = (_Float16)f1.z; b.h[1] = (_Float16)f1.w; pk.y = b.u;
      *(uint2*)((char*)f16 + (size_t)r1 * 256 + (size_t)k4 * 8) = pk;
    }
    #pragma unroll
    for (int kk = 0; kk < 4; ++kk) {
      int k = 4 * k4 + kk;
      float fv0 = (kk == 0) ? f0.x : (kk == 1) ? f0.y : (kk == 2) ? f0.z : f0.w;
      float fv1 = (kk == 0) ? f1.x : (kk == 1) ? f1.y : (kk == 2) ? f1.z : f1.w;
      float4 w0 = *(const float4*)&sA[k * 64 + jg];
      float4 w1 = *(const float4*)&sA[k * 64 + jg + 4];
      acc0[0] += fv0 * w0.x; acc0[1] += fv0 * w0.y; acc0[2] += fv0 * w0.z; acc0[3] += fv0 * w0.w;
      acc0[4] += fv0 * w1.x; acc0[5] += fv0 * w1.y; acc0[6] += fv0 * w1.z; acc0[7] += fv0 * w1.w;
      acc1[0] += fv1 * w0.x; acc1[1] += fv1 * w0.y; acc1[2] += fv1 * w0.z; acc1[3] += fv1 * w0.w;
      acc1[4] += fv1 * w1.x; acc1[5] += fv1 * w1.y; acc1[6] += fv1 * w1.z; acc1[7] += fv1 * w1.w;
    }
  }
  U32H2 t0, t1, t2, t3;
  uint4 o;
  t0.h[0]=(_Float16)acc0[0]; t0.h[1]=(_Float16)acc0[1];
  t1.h[0]=(_Float16)acc0[2]; t1.h[1]=(_Float16)acc0[3];
  t2.h[0]=(_Float16)acc0[4]; t2.h[1]=(_Float16)acc0[5];
  t3.h[0]=(_Float16)acc0[6]; t3.h[1]=(_Float16)acc0[7];
  o.x=t0.u; o.y=t1.u; o.z=t2.u; o.w=t3.u;
  *(uint4*)((char*)p16 + (size_t)r0 * 128 + (size_t)jg * 2) = o;
  t0.h[0]=(_Float16)acc1[0]; t0.h[1]=(_Float16)acc1[1];
  t1.h[0]=(_Float16)acc1[2]; t1.h[1]=(_Float16)acc1[3];
  t2.h[0]=(_Float16)acc1[4]; t2.h[1]=(_Float16)acc1[5];
  t3.h[0]=(_Float16)acc1[6]; t3.h[1]=(_Float16)acc1[7];
  o.x=t0.u; o.y=t1.u; o.z=t2.u; o.w=t3.u;
  *(uint4*)((char*)p16 + (size_t)r1 * 128 + (size_t)jg * 2) = o;
}

// ---------------- edge kernel helpers ----------------
__device__ __forceinline__ float grp_dist_f16(uint4 au, uint4 bu) {
  U4H2 a, b; a.u = au; b.u = bu;
  float ssd = 0.f;
  #pragma unroll
  for (int p = 0; p < 4; ++p) { h2 d = a.h[p] - b.h[p]; ssd = fdot2f(d, d, ssd); }
  ssd += __shfl_xor(ssd, 1, 64);
  ssd += __shfl_xor(ssd, 2, 64);
  ssd += __shfl_xor(ssd, 4, 64);
  ssd += __shfl_xor(ssd, 8, 64);
  return sqrtf(ssd);
}

__device__ __forceinline__ unsigned h1pack(unsigned puv, unsigned quv, float dist, float i1,
                                           float w1l0, float w1l1, float bb0, float bb1) {
  U32H2 p, q; p.u = puv; q.u = quv;
  float h0  = fmaxf(fmaf((float)p.h[0] + (float)q.h[0], i1, fmaf(dist, w1l0, bb0)), 0.f);
  float h1v = fmaxf(fmaf((float)p.h[1] + (float)q.h[1], i1, fmaf(dist, w1l1, bb1)), 0.f);
  U32H2 r; r.h[0] = (_Float16)h0; r.h[1] = (_Float16)h1v;
  return r.u;
}

// ---------------- fused edge kernel ----------------
// Phase 0: per-thread index preload -> LDS (rs/rt computed once).
// Phase 1: 16-lane groups, 2-edge batched prefetch (feat16 rows + P16 slices) -> dist -> h1 -> ht.
// Phase 2: thread-per-edge tail: W2 half2 via scalar loads + fdot2.
template <bool F16>
__global__ __launch_bounds__(256, 8) void edge_fused(const float* __restrict__ feat,
                                                     const float* __restrict__ ws,
                                                     const float* __restrict__ b1,
                                                     const float* __restrict__ b2,
                                                     const float* __restrict__ b3,
                                                     const int* __restrict__ bids,
                                                     const int* __restrict__ srcs,
                                                     const int* __restrict__ tgts,
                                                     float* __restrict__ out, int E) {
  __shared__ unsigned ht[256 * 17];   // h1 tile as half2, padded stride
  __shared__ int sRS[256], sRT[256];
  int tid = threadIdx.x;
  int lane = tid & 15;
  int grp  = tid >> 4;

  const __half* feat16 = (const __half*)(ws + OFF_F16);
  const __half* p16    = (const __half*)(ws + OFF_P16);
  const unsigned* w2h  = (const unsigned*)(ws + OFF_W2H);

  float i1 = ws[OFF_I1];
  int j0 = 2 * lane;
  float w1l0 = ws[OFF_W1L + j0];
  float w1l1 = ws[OFF_W1L + j0 + 1];
  float bb0  = b1[j0];
  float bb1  = b1[j0 + 1];
  float bias3 = b3[0];

  for (int base = blockIdx.x * 256; base < E; base += gridDim.x * 256) {
    // ---- phase 0: index preload ----
    int e0 = base + tid;
    if (e0 < E) {
      int b = bids[e0];
      sRS[tid] = b * NNODES + srcs[e0];
      sRT[tid] = b * NNODES + tgts[e0];
    }
    __syncthreads();

    // ---- phase 1 ----
    if (F16 && (base + 256 <= E)) {
      #pragma unroll 1
      for (int rr = 0; rr < 8; ++rr) {
        int el0 = (rr * 2 + 0) * 16 + grp;
        int el1 = (rr * 2 + 1) * 16 + grp;
        int rs0 = sRS[el0], rt0 = sRT[el0];
        int rs1 = sRS[el1], rt1 = sRT[el1];
        // issue all 4 row loads + 4 P loads before consuming anything
        uint4 a0 = *(const uint4*)((const char*)feat16 + ((size_t)rs0 << 8) + (lane << 4));
        uint4 c0 = *(const uint4*)((const char*)feat16 + ((size_t)rt0 << 8) + (lane << 4));
        uint4 a1 = *(const uint4*)((const char*)feat16 + ((size_t)rs1 << 8) + (lane << 4));
        uint4 c1 = *(const uint4*)((const char*)feat16 + ((size_t)rt1 << 8) + (lane << 4));
        unsigned pu0 = *(const unsigned*)((const char*)p16 + ((size_t)rs0 << 7) + (lane << 2));
        unsigned qu0 = *(const unsigned*)((const char*)p16 + ((size_t)rt0 << 7) + 64 + (lane << 2));
        unsigned pu1 = *(const unsigned*)((const char*)p16 + ((size_t)rs1 << 7) + (lane << 2));
        unsigned qu1 = *(const unsigned*)((const char*)p16 + ((size_t)rt1 << 7) + 64 + (lane << 2));
        float d0 = grp_dist_f16(a0, c0);
        float d1 = grp_dist_f16(a1, c1);
        ht[el0 * 17 + lane] = h1pack(pu0, qu0, d0, i1, w1l0, w1l1, bb0, bb1);
        ht[el1 * 17 + lane] = h1pack(pu1, qu1, d1, i1, w1l0, w1l1, bb0, bb1);
      }
    } else {
      #pragma unroll 2
      for (int r = 0; r < 16; ++r) {
        int el = r * 16 + grp;
        int e  = base + el;
        if (e < E) {
          int rs = sRS[el], rt = sRT[el];
          float dist;
          if (F16) {
            uint4 au = *(const uint4*)((const char*)feat16 + ((size_t)rs << 8) + (lane << 4));
            uint4 bu = *(const uint4*)((const char*)feat16 + ((size_t)rt << 8) + (lane << 4));
            dist = grp_dist_f16(au, bu);
          } else {
            const float4* A  = (const float4*)&feat[(size_t)rs * FEATD];
            const float4* Bp = (const float4*)&feat[(size_t)rt * FEATD];
            float ssd = 0.f;
            #pragma unroll
            for (int p = 0; p < 2; ++p) {
              float4 a = A[lane * 2 + p], c = Bp[lane * 2 + p];
              float dx = a.x - c.x, dy = a.y - c.y, dz = a.z - c.z, dw = a.w - c.w;
              ssd += dx * dx + dy * dy + dz * dz + dw * dw;
            }
            ssd += __shfl_xor(ssd, 1, 64);
            ssd += __shfl_xor(ssd, 2, 64);
            ssd += __shfl_xor(ssd, 4, 64);
            ssd += __shfl_xor(ssd, 8, 64);
            dist = sqrtf(ssd);
          }
          unsigned puv = *(const unsigned*)((const char*)p16 + ((size_t)rs << 7) + (lane << 2));
          unsigned quv = *(const unsigned*)((const char*)p16 + ((size_t)rt << 7) + 64 + (lane << 2));
          ht[el * 17 + lane] = h1pack(puv, quv, dist, i1, w1l0, w1l1, bb0, bb1);
        }
      }
    }
    __syncthreads();

    // ---- phase 2: thread-per-edge tail (W2 via scalar loads + fdot2) ----
    int e = base + tid;
    if (e < E) {
      unsigned hrow[16];
      #pragma unroll
      for (int q = 0; q < 16; ++q) hrow[q] = ht[tid * 17 + q];
      float la = bias3;
      #pragma unroll
      for (int j = 0; j < 32; ++j) {
        float acc = b2[j];
        #pragma unroll
        for (int q = 0; q < 16; ++q) {
          U32H2 w; w.u = w2h[j * 16 + q];
          U32H2 h; h.u = hrow[q];
          acc = fdot2f(w.h, h.h, acc);
        }
        la += ws[OFF_W3 + j] * fmaxf(acc, 0.f);
      }
      la = fminf(fmaxf(la, -5.f), 5.f);
      out[e]     = 1.0f / (1.0f + exp2f(la * -2.18590179f));
      out[E + e] = la;
    }
    __syncthreads();
  }
}

// ---------------- fallback path (tiny ws): full spectral + in-loop W1, all f32 ----------------
__global__ __launch_bounds__(256) void spectral_full(const float* __restrict__ W1,
                                                     const float* __restrict__ W2,
                                                     const float* __restrict__ W3,
                                                     float* __restrict__ ws) {
  __shared__ float sA[32 * 257];
  __shared__ float u[32], v[257];
  __shared__ float red[8];
  int tid = threadIdx.x;
  float sig1 = spectral_sigma_t<32, 257>(W1, sA, u, v, red);
  float i1 = 1.0f / sig1;
  for (int idx = tid; idx < 128 * 64; idx += 256) {
    int k = idx >> 6, jj = idx & 63;
    float w = (jj < 32) ? sA[jj * 257 + k] : sA[(jj - 32) * 257 + 128 + k];
    ws[OFF_FBWT + idx] = w * i1;
  }
  for (int j = tid; j < 32; j += 256) ws[OFF_W1L + j] = sA[j * 257 + 256] * i1;
  __syncthreads();
  float sig2 = spectral_sigma_t<32, 32>(W2, sA, u, v, red);
  float i2 = 1.0f / sig2;
  for (int idx = tid; idx < 1024; idx += 256) ws[OFF_W2 + idx] = sA[idx] * i2;
  __syncthreads();
  float sig3 = spectral_sigma_t<1, 32>(W3, sA, u, v, red);
  float i3 = 1.0f / sig3;
  for (int k = tid; k < 32; k += 256) ws[OFF_W3 + k] = sA[k] * i3;
}

__global__ __launch_bounds__(256) void edge_kernel_nop(const float* __restrict__ feat,
                                                       const float* __restrict__ ws,
                                                       const float* __restrict__ b1,
                                                       const float* __restrict__ b2,
                                                       const float* __restrict__ b3,
                                                       const int* __restrict__ bids,
                                                       const int* __restrict__ srcs,
                                                       const int* __restrict__ tgts,
                                                       float* __restrict__ out, int E) {
  __shared__ float sWt[128 * 64];
  __shared__ float sW2[1024];
  __shared__ float sW3[32], sW1l[32], sB1[32], sB2[32];
  int tid = threadIdx.x;
  for (int i = tid * 4; i < 128 * 64; i += 256 * 4)
    *(float4*)&sWt[i] = *(const float4*)&ws[OFF_FBWT + i];
  for (int i = tid; i < 1024; i += 256) sW2[i] = ws[OFF_W2 + i];
  if (tid < 32) {
    sW3[tid]  = ws[OFF_W3 + tid];
    sW1l[tid] = ws[OFF_W1L + tid];
    sB1[tid]  = b1[tid];
    sB2[tid]  = b2[tid];
  }
  __syncthreads();
  float bias3 = b3[0];

  for (int e = blockIdx.x * 256 + tid; e < E; e += gridDim.x * 256) {
    int b = bids[e], s = srcs[e], t = tgts[e];
    const float4* A  = (const float4*)&feat[(size_t)(b * NNODES + s) * FEATD];
    const float4* Bp = (const float4*)&feat[(size_t)(b * NNODES + t) * FEATD];
    float ssd = 0.f;
    float h1p[32];
    #pragma unroll
    for (int j = 0; j < 32; ++j) h1p[j] = 0.f;
    #pragma unroll 1
    for (int k4 = 0; k4 < 32; ++k4) {
      float4 a = A[k4], c = Bp[k4];
      float dx = a.x - c.x, dy = a.y - c.y, dz = a.z - c.z, dw = a.w - c.w;
      ssd += dx * dx + dy * dy + dz * dz + dw * dw;
      #pragma unroll
      for (int kk = 0; kk < 4; ++kk) {
        int k = 4 * k4 + kk;
        float fa = (kk == 0) ? a.x : (kk == 1) ? a.y : (kk == 2) ? a.z : a.w;
        float fc = (kk == 0) ? c.x : (kk == 1) ? c.y : (kk == 2) ? c.z : c.w;
        #pragma unroll
        for (int q = 0; q < 8; ++q) {
          float4 w0 = *(const float4*)&sWt[k * 64 + 4 * q];
          float4 w1 = *(const float4*)&sWt[k * 64 + 32 + 4 * q];
          h1p[4*q+0] += fa * w0.x + fc * w1.x;
          h1p[4*q+1] += fa * w0.y + fc * w1.y;
          h1p[4*q+2] += fa * w0.z + fc * w1.z;
          h1p[4*q+3] += fa * w0.w + fc * w1.w;
        }
      }
    }
    float dist = sqrtf(ssd);
    float h1[32];
    #pragma unroll
    for (int j = 0; j < 32; ++j)
      h1[j] = fmaxf(h1p[j] + dist * sW1l[j] + sB1[j], 0.f);
    float la = bias3;
    #pragma unroll
    for (int j = 0; j < 32; ++j) {
      float acc = sB2[j];
      #pragma unroll
      for (int q = 0; q < 8; ++q) {
        float4 w = *(const float4*)&sW2[j * 32 + 4 * q];
        acc += w.x * h1[4 * q] + w.y * h1[4 * q + 1] + w.z * h1[4 * q + 2] + w.w * h1[4 * q + 3];
      }
      la += sW3[j] * fmaxf(acc, 0.f);
    }
    la = fminf(fmaxf(la, -5.f), 5.f);
    out[e]     = 1.0f / (1.0f + __expf(-la / 0.66f));
    out[E + e] = la;
  }
}

extern "C" void kernel_launch(void* const* d_in, const int* in_sizes, int n_in,
                              void* d_out, int out_size, void* d_ws, size_t ws_size,
                              hipStream_t stream) {
  const float* feat = (const float*)d_in[0];
  const float* W1   = (const float*)d_in[1];
  const float* b1   = (const float*)d_in[2];
  const float* W2   = (const float*)d_in[3];
  const float* b2   = (const float*)d_in[4];
  const float* W3   = (const float*)d_in[5];
  const float* b3   = (const float*)d_in[6];
  const int* bids   = (const int*)d_in[7];
  const int* srcs   = (const int*)d_in[8];
  const int* tgts   = (const int*)d_in[9];
  float* out = (float*)d_out;
  float* ws  = (float*)d_ws;
  int E = in_sizes[7];

  size_t need_p   = (size_t)OFF_F16 * sizeof(float);                       // P16 only
  size_t need_f16 = (size_t)(OFF_F16 + F16_FLOATS) * sizeof(float);        // + feat16
  int egrid = (E + 255) / 256;

  if (ws_size >= need_f16) {
    prep_kernel<<<dim3(626), dim3(256), 0, stream>>>(feat, W1, W2, W3, ws, 1);
    edge_fused<true><<<dim3(egrid), dim3(256), 0, stream>>>(feat, ws, b1, b2, b3,
                                                            bids, srcs, tgts, out, E);
  } else if (ws_size >= need_p) {
    prep_kernel<<<dim3(626), dim3(256), 0, stream>>>(feat, W1, W2, W3, ws, 0);
    edge_fused<false><<<dim3(egrid), dim3(256), 0, stream>>>(feat, ws, b1, b2, b3,
                                                             bids, srcs, tgts, out, E);
  } else {
    spectral_full<<<dim3(1), dim3(256), 0, stream>>>(W1, W2, W3, ws);
    edge_kernel_nop<<<dim3(egrid), dim3(256), 0, stream>>>(feat, ws, b1, b2, b3,
                                                           bids, srcs, tgts, out, E);
  }
}